// Round 4
// baseline (9617.525 us; speedup 1.0000x reference)
//
#include <hip/hip_runtime.h>

typedef __attribute__((ext_vector_type(8))) short short8;
typedef __attribute__((ext_vector_type(4))) float f32x4;
typedef unsigned short u16;
typedef unsigned long long u64;

#define TP   1022      // conv output length = T-2
#define NWG  64        // workgroups in persistent LSTM kernel

// ws layout (byte offsets, all 256-aligned)
#define OFF_WPACK   0            // 2048*576*2   = 2359296
#define OFF_SEQ     2359296      // 1022*64*64*2 = 8372224
#define OFF_BIAS    10993664     // 2048*4       = 8192
#define OFF_H0      11001856     // 64*512*2     = 65536
#define OFF_H1      11067392     // 64*512*2     = 65536
#define OFF_HFIN    11132928     // 64*512*4     = 131072
#define OFF_BAR     11264000     // slots[64]

__device__ inline u16 f2bf(float x) {
  union { float f; unsigned u; } un; un.f = x;
  unsigned r = un.u + 0x7fffu + ((un.u >> 16) & 1u);  // RNE
  return (u16)(r >> 16);
}
__device__ inline float sigmoidf_(float x) { return 1.f / (1.f + __expf(-x)); }
__device__ inline float tanhf_(float x)    { return 2.f / (1.f + __expf(-2.f * x)) - 1.f; }

// ---- init: zero h buffers + barrier slots, build packed bias (b_ih+b_hh, n=4j+g order)
__global__ void k_init(const float* __restrict__ b_ih, const float* __restrict__ b_hh,
                       float* __restrict__ biasp, unsigned* __restrict__ hzero,
                       unsigned* __restrict__ bar) {
  int tid = blockIdx.x * 256 + threadIdx.x;
  if (tid < 32768) hzero[tid] = 0u;                 // both h bufs (131072 B)
  if (tid < 2048) {
    int j = tid >> 2, g = tid & 3;
    int row = g * 512 + j;
    biasp[tid] = b_ih[row] + b_hh[row];
  }
  if (tid < 128) bar[tid] = 0u;                     // slots
}

// ---- pack W = [w_ih ; w_hh] (2048 x 576) into MFMA A-fragment order, bf16.
// packed gate-row n = 4*j + g.  per (mtile,ktile): lane holds row n0+(lane&15),
// k = k0 + (lane>>4)*8 + i, 8 contiguous bf16 per lane.
__global__ void k_pack(const float* __restrict__ w_ih, const float* __restrict__ w_hh,
                       u16* __restrict__ wp) {
  int idx = blockIdx.x * 256 + threadIdx.x;        // < 128*18*512 = 1179648
  int nt = idx / 9216;
  int rem = idx - nt * 9216;
  int kt = rem / 512;
  int rem2 = rem - kt * 512;
  int lane = rem2 >> 3, i = rem2 & 7;
  int n = nt * 16 + (lane & 15);
  int k = kt * 32 + (lane >> 4) * 8 + i;
  int j = n >> 2, g = n & 3;
  int row = g * 512 + j;
  float v = (k < 64) ? w_ih[row * 64 + k] : w_hh[row * 512 + (k - 64)];
  wp[idx] = f2bf(v);
}

// ---- normalize (fused) + conv1d(k=3, VALID) + relu -> seq[t][b][oc] bf16
__global__ __launch_bounds__(256) void k_conv(const float* __restrict__ inX,
                                              const float* __restrict__ conv_w,
                                              const float* __restrict__ conv_b,
                                              u16* __restrict__ seq) {
  __shared__ float xn[6][128];
  __shared__ float rn[6];
  int b = blockIdx.y;
  int t0 = blockIdx.x * 4;
  int tid = threadIdx.x;
  for (int e = tid; e < 768; e += 256) {
    int ri = e >> 7, col = e & 127;
    int t = t0 + ri;
    xn[ri][col] = (t < 1024) ? inX[((size_t)b * 1024 + t) * 128 + col] : 0.f;
  }
  __syncthreads();
  if (tid < 192) {                                 // 6 rows x 32 lanes
    int ri = tid >> 5, l32 = tid & 31;
    float4 v = *reinterpret_cast<const float4*>(&xn[ri][l32 * 4]);
    float s = v.x * v.x + v.y * v.y + v.z * v.z + v.w * v.w;
    #pragma unroll
    for (int d = 1; d < 32; d <<= 1) s += __shfl_xor(s, d, 32);
    if (l32 == 0) rn[ri] = 1.f / fmaxf(sqrtf(s), 1e-12f);
  }
  __syncthreads();
  for (int e = tid; e < 768; e += 256) {
    int ri = e >> 7, col = e & 127;
    xn[ri][col] *= rn[ri];
  }
  __syncthreads();
  int oc = tid & 63, ty = tid >> 6;
  int t = t0 + ty;
  if (t < TP) {
    const float* wr = conv_w + oc * 384;           // (OC, IN, 3) row-major
    float s = conv_b[oc];
    #pragma unroll 4
    for (int i = 0; i < 128; ++i) {
      s += wr[i * 3 + 0] * xn[ty + 0][i]
         + wr[i * 3 + 1] * xn[ty + 1][i]
         + wr[i * 3 + 2] * xn[ty + 2][i];
    }
    s = fmaxf(s, 0.f);
    seq[((size_t)t * 64 + b) * 64 + oc] = f2bf(s);
  }
}

// ---- persistent LSTM, operand-swapped: C = W(gate rows) x [x;h](batch cols).
// Fence-free cross-XCD h exchange: all h traffic via relaxed agent-scope atomics
// (sc1 path, coherence point). NO buffer_inv / wbl2 in the loop -> weights & seq
// stay L2/VGPR resident. Ordering via __syncthreads (drains vmcnt) + data deps.
__global__ __launch_bounds__(256, 1) void k_lstm(const u16* __restrict__ seq,
                                                 const u16* __restrict__ wp,
                                                 const float* __restrict__ biasp,
                                                 u16* h0buf, u16* h1buf,
                                                 float* __restrict__ hfin,
                                                 unsigned* bar) {
  const int wg = blockIdx.x;
  const int tid = threadIdx.x;
  const int wave = tid >> 6, lane = tid & 63;
  const int wgl = wg * 4 + wave;                   // 0..255
  const int mt = wgl >> 1;                         // 0..127 gate m-tile (= 2wg + (wave>>1))
  const int nh = wgl & 1;                          // batch half
  const int b0n = nh * 32 + (lane & 15);           // batch (n-tile 0)
  const int b1n = b0n + 16;                        // batch (n-tile 1)
  const int hi = lane >> 4;                        // 0..3
  const int koff = hi * 8;
  const int u = mt * 4 + hi;                       // this lane's hidden unit
  const int uloc = 4 * (wave >> 1) + hi;           // unit within WG's 8-unit slice
  const float4 bias4 = *reinterpret_cast<const float4*>(biasp + mt * 16 + hi * 4);

  __shared__ u16 stage[64][8];                     // h staging: [batch][unit-slice]

  // preload this wave's weight slice into registers: 18 k-tiles x 8 bf16/lane
  short8 w[18];
  {
    const u16* wbase = wp + (size_t)mt * (18 * 512) + lane * 8;
    #pragma unroll
    for (int kt = 0; kt < 18; ++kt) w[kt] = *reinterpret_cast<const short8*>(wbase + kt * 512);
  }

  unsigned* slots = bar;
  float c0 = 0.f, c1 = 0.f;
  f32x4 acc0, acc1;

  union HU { u64 q[2]; short8 v; };

#define XPART(T) do { \
    const u16* xt_ = seq + (size_t)(T) * 4096; \
    short8 x0a = *reinterpret_cast<const short8*>(xt_ + b0n * 64 + koff); \
    short8 x1a = *reinterpret_cast<const short8*>(xt_ + b1n * 64 + koff); \
    short8 x0b = *reinterpret_cast<const short8*>(xt_ + b0n * 64 + 32 + koff); \
    short8 x1b = *reinterpret_cast<const short8*>(xt_ + b1n * 64 + 32 + koff); \
    f32x4 z_ = {0.f, 0.f, 0.f, 0.f}; \
    acc0 = __builtin_amdgcn_mfma_f32_16x16x32_bf16(w[0], x0a, z_, 0, 0, 0); \
    acc1 = __builtin_amdgcn_mfma_f32_16x16x32_bf16(w[0], x1a, z_, 0, 0, 0); \
    acc0 = __builtin_amdgcn_mfma_f32_16x16x32_bf16(w[1], x0b, acc0, 0, 0, 0); \
    acc1 = __builtin_amdgcn_mfma_f32_16x16x32_bf16(w[1], x1b, acc1, 0, 0, 0); \
  } while (0)

  XPART(0);                                        // x-part for t=0 (h(-1)=0)

  for (int t = 0; t < TP; ++t) {
    // ---- wait for h(t-1): every WG's wave 0 polls all 64 slots directly
    if (t > 0) {
      if (wave == 0) {
        const unsigned tgt = (unsigned)t;
        for (;;) {
          unsigned v = __hip_atomic_load(&slots[lane], __ATOMIC_RELAXED, __HIP_MEMORY_SCOPE_AGENT);
          if (__all(v >= tgt)) break;
          __builtin_amdgcn_s_sleep(1);
        }
      }
      __syncthreads();                             // full compiler+HW barrier
    }

    const u16* hc = (t & 1) ? h1buf : h0buf;
    u16* hn = (t & 1) ? h0buf : h1buf;

    // ---- recurrent part: 16 k-tiles over h(t-1), coherent 8B atomic loads
    #pragma unroll
    for (int kt = 2; kt < 18; ++kt) {
      const u16* p0 = hc + b0n * 512 + (kt - 2) * 32 + koff;
      const u16* p1 = hc + b1n * 512 + (kt - 2) * 32 + koff;
      HU u0, u1;
      u0.q[0] = __hip_atomic_load((const u64*)p0,       __ATOMIC_RELAXED, __HIP_MEMORY_SCOPE_AGENT);
      u0.q[1] = __hip_atomic_load((const u64*)(p0 + 4), __ATOMIC_RELAXED, __HIP_MEMORY_SCOPE_AGENT);
      u1.q[0] = __hip_atomic_load((const u64*)p1,       __ATOMIC_RELAXED, __HIP_MEMORY_SCOPE_AGENT);
      u1.q[1] = __hip_atomic_load((const u64*)(p1 + 4), __ATOMIC_RELAXED, __HIP_MEMORY_SCOPE_AGENT);
      acc0 = __builtin_amdgcn_mfma_f32_16x16x32_bf16(w[kt], u0.v, acc0, 0, 0, 0);
      acc1 = __builtin_amdgcn_mfma_f32_16x16x32_bf16(w[kt], u1.v, acc1, 0, 0, 0);
    }

    // ---- gates (i,f,g,o all in this lane's acc[0..3])
    float i0 = sigmoidf_(acc0[0] + bias4.x);
    float f0 = sigmoidf_(acc0[1] + bias4.y);
    float g0 = tanhf_(acc0[2] + bias4.z);
    float o0 = sigmoidf_(acc0[3] + bias4.w);
    c0 = f0 * c0 + i0 * g0;
    float hv0 = o0 * tanhf_(c0);
    float i1 = sigmoidf_(acc1[0] + bias4.x);
    float f1 = sigmoidf_(acc1[1] + bias4.y);
    float g1 = tanhf_(acc1[2] + bias4.z);
    float o1 = sigmoidf_(acc1[3] + bias4.w);
    c1 = f1 * c1 + i1 * g1;
    float hv1 = o1 * tanhf_(c1);

    // ---- stage h in LDS (WG owns units [8wg, 8wg+8) x all 64 batches)
    stage[b0n][uloc] = f2bf(hv0);
    stage[b1n][uloc] = f2bf(hv1);
    if (t == TP - 1) {
      hfin[b0n * 512 + u] = hv0;                   // fp32, normal stores (kernel
      hfin[b1n * 512 + u] = hv1;                   // boundary flushes for k_fc)
    }
    __syncthreads();

    // ---- coalesced coherent h stores: 128 threads x 8B
    if (tid < 128) {
      int b = tid >> 1, half = tid & 1;
      u64 val = *reinterpret_cast<const u64*>(&stage[b][half * 4]);
      __hip_atomic_store((u64*)(hn + b * 512 + wg * 8 + half * 4), val,
                         __ATOMIC_RELAXED, __HIP_MEMORY_SCOPE_AGENT);
    }
    __syncthreads();                               // drains vmcnt -> stores visible

    if (tid == 0)
      __hip_atomic_store(&slots[wg], (unsigned)(t + 1), __ATOMIC_RELAXED, __HIP_MEMORY_SCOPE_AGENT);

    // ---- x-part prefetch for t+1 (normal cached loads; seq stays L2-resident)
    if (t + 1 < TP) XPART(t + 1);
  }
#undef XPART
}

// ---- final linear: out[b][o] = h . lin_w[o] + lin_b[o]  (fp32)
__global__ void k_fc(const float* __restrict__ hfin, const float* __restrict__ lin_w,
                     const float* __restrict__ lin_b, float* __restrict__ out) {
  int b = blockIdx.x, o = threadIdx.x;             // 128 threads
  const float* hp = hfin + b * 512;
  const float* wq = lin_w + o * 512;
  float s = lin_b[o];
  #pragma unroll 4
  for (int j = 0; j < 512; ++j) s += hp[j] * wq[j];
  out[b * 128 + o] = s;
}

extern "C" void kernel_launch(void* const* d_in, const int* in_sizes, int n_in,
                              void* d_out, int out_size, void* d_ws, size_t ws_size,
                              hipStream_t stream) {
  const float* inX    = (const float*)d_in[0];
  const float* conv_w = (const float*)d_in[2];
  const float* conv_b = (const float*)d_in[3];
  const float* w_ih   = (const float*)d_in[4];
  const float* w_hh   = (const float*)d_in[5];
  const float* b_ih   = (const float*)d_in[6];
  const float* b_hh   = (const float*)d_in[7];
  const float* lin_w  = (const float*)d_in[8];
  const float* lin_b  = (const float*)d_in[9];
  float* out = (float*)d_out;
  char* ws = (char*)d_ws;
  u16*      wpack = (u16*)(ws + OFF_WPACK);
  u16*      seq   = (u16*)(ws + OFF_SEQ);
  float*    biasp = (float*)(ws + OFF_BIAS);
  u16*      h0b   = (u16*)(ws + OFF_H0);
  u16*      h1b   = (u16*)(ws + OFF_H1);
  float*    hfin  = (float*)(ws + OFF_HFIN);
  unsigned* bar   = (unsigned*)(ws + OFF_BAR);

  k_init<<<dim3(128), dim3(256), 0, stream>>>(b_ih, b_hh, biasp, (unsigned*)(ws + OFF_H0), bar);
  k_pack<<<dim3(4608), dim3(256), 0, stream>>>(w_ih, w_hh, wpack);
  k_conv<<<dim3(256, 64), dim3(256), 0, stream>>>(inX, conv_w, conv_b, seq);
  k_lstm<<<dim3(NWG), dim3(256), 0, stream>>>(seq, wpack, biasp, h0b, h1b, hfin, bar);
  k_fc<<<dim3(64), dim3(128), 0, stream>>>(hfin, lin_w, lin_b, out);
}

// Round 5
// 6788.882 us; speedup vs baseline: 1.4167x; 1.4167x over previous
//
#include <hip/hip_runtime.h>

typedef __attribute__((ext_vector_type(8))) short short8;
typedef __attribute__((ext_vector_type(4))) float f32x4;
typedef unsigned short u16;
typedef unsigned long long u64;

#define TP   1022      // conv output length = T-2
#define NWRK 32        // worker WGs (all on one XCD)

// ws layout (byte offsets, all 256-aligned)
#define OFF_WPACK   0            // 2048*576*2   = 2359296
#define OFF_SEQ     2359296      // 1022*64*64*2 = 8372224
#define OFF_BIAS    10993664     // 2048*4       = 8192
#define OFF_H0      11001856     // 64*512*2     = 65536
#define OFF_H1      11067392     // 64*512*2     = 65536
#define OFF_HFIN    11132928     // 64*512*4     = 131072
#define OFF_BAR     11264000     // slots[32] @0, xcdcnt[8] @32, designated @40

__device__ inline u16 f2bf(float x) {
  union { float f; unsigned u; } un; un.f = x;
  unsigned r = un.u + 0x7fffu + ((un.u >> 16) & 1u);  // RNE
  return (u16)(r >> 16);
}
__device__ inline float sigmoidf_(float x) { return 1.f / (1.f + __expf(-x)); }
__device__ inline float tanhf_(float x)    { return 2.f / (1.f + __expf(-2.f * x)) - 1.f; }

// 16B load/store that bypass L1 but are served by the XCD-local L2 (sc0 only).
__device__ inline f32x4 load16_sc0(const void* p) {
  f32x4 r;
  asm volatile("global_load_dwordx4 %0, %1, off sc0" : "=v"(r) : "v"(p) : "memory");
  return r;
}
__device__ inline void store16_sc0(void* p, f32x4 v) {
  asm volatile("global_store_dwordx4 %0, %1, off sc0" :: "v"(p), "v"(v) : "memory");
}

// ---- init: zero h buffers + barrier region, build packed bias (b_ih+b_hh, n=4j+g)
__global__ void k_init(const float* __restrict__ b_ih, const float* __restrict__ b_hh,
                       float* __restrict__ biasp, unsigned* __restrict__ hzero,
                       unsigned* __restrict__ bar) {
  int tid = blockIdx.x * 256 + threadIdx.x;
  if (tid < 32768) hzero[tid] = 0u;                 // both h bufs (131072 B)
  if (tid < 2048) {
    int j = tid >> 2, g = tid & 3;
    int row = g * 512 + j;
    biasp[tid] = b_ih[row] + b_hh[row];
  }
  if (tid < 128) bar[tid] = 0u;                     // slots + xcdcnt + designated
}

// ---- pack W = [w_ih ; w_hh] (2048 x 576) into MFMA A-fragment order, bf16.
__global__ void k_pack(const float* __restrict__ w_ih, const float* __restrict__ w_hh,
                       u16* __restrict__ wp) {
  int idx = blockIdx.x * 256 + threadIdx.x;        // < 128*18*512 = 1179648
  int nt = idx / 9216;
  int rem = idx - nt * 9216;
  int kt = rem / 512;
  int rem2 = rem - kt * 512;
  int lane = rem2 >> 3, i = rem2 & 7;
  int n = nt * 16 + (lane & 15);
  int k = kt * 32 + (lane >> 4) * 8 + i;
  int j = n >> 2, g = n & 3;
  int row = g * 512 + j;
  float v = (k < 64) ? w_ih[row * 64 + k] : w_hh[row * 512 + (k - 64)];
  wp[idx] = f2bf(v);
}

// ---- normalize (fused) + conv1d(k=3, VALID) + relu -> seq[t][b][oc] bf16
__global__ __launch_bounds__(256) void k_conv(const float* __restrict__ inX,
                                              const float* __restrict__ conv_w,
                                              const float* __restrict__ conv_b,
                                              u16* __restrict__ seq) {
  __shared__ float xn[6][128];
  __shared__ float rn[6];
  int b = blockIdx.y;
  int t0 = blockIdx.x * 4;
  int tid = threadIdx.x;
  for (int e = tid; e < 768; e += 256) {
    int ri = e >> 7, col = e & 127;
    int t = t0 + ri;
    xn[ri][col] = (t < 1024) ? inX[((size_t)b * 1024 + t) * 128 + col] : 0.f;
  }
  __syncthreads();
  if (tid < 192) {                                 // 6 rows x 32 lanes
    int ri = tid >> 5, l32 = tid & 31;
    float4 v = *reinterpret_cast<const float4*>(&xn[ri][l32 * 4]);
    float s = v.x * v.x + v.y * v.y + v.z * v.z + v.w * v.w;
    #pragma unroll
    for (int d = 1; d < 32; d <<= 1) s += __shfl_xor(s, d, 32);
    if (l32 == 0) rn[ri] = 1.f / fmaxf(sqrtf(s), 1e-12f);
  }
  __syncthreads();
  for (int e = tid; e < 768; e += 256) {
    int ri = e >> 7, col = e & 127;
    xn[ri][col] *= rn[ri];
  }
  __syncthreads();
  int oc = tid & 63, ty = tid >> 6;
  int t = t0 + ty;
  if (t < TP) {
    const float* wr = conv_w + oc * 384;           // (OC, IN, 3) row-major
    float s = conv_b[oc];
    #pragma unroll 4
    for (int i = 0; i < 128; ++i) {
      s += wr[i * 3 + 0] * xn[ty + 0][i]
         + wr[i * 3 + 1] * xn[ty + 1][i]
         + wr[i * 3 + 2] * xn[ty + 2][i];
    }
    s = fmaxf(s, 0.f);
    seq[((size_t)t * 64 + b) * 64 + oc] = f2bf(s);
  }
}

// ---- persistent LSTM on ONE XCD. 256 WGs launched; one XCD self-designates
// (pigeonhole: some XCD hosts >=32 of 256 WGs); its 32 ranked WGs (on 32 distinct
// CUs at 1 WG/CU) run the recurrence with all h exchange through the XCD-local L2
// (sc0 loads/stores, workgroup-scope atomic RMW slots). Everyone else exits.
// Wave owns 2 m-tiles (8 gate rows = 8 units across 2 mt) x 1 batch-half.
__global__ __launch_bounds__(256, 1) void k_lstm(const u16* __restrict__ seq,
                                                 const u16* __restrict__ wp,
                                                 const float* __restrict__ biasp,
                                                 u16* h0buf, u16* h1buf,
                                                 float* __restrict__ hfin,
                                                 unsigned* bar) {
  const int tid = threadIdx.x;
  __shared__ int s_rank;

  // ---- XCD self-designation (setup only; agent-scope atomics via MALL)
  if (tid == 0) {
    unsigned xcd;
    asm volatile("s_getreg_b32 %0, hwreg(HW_REG_XCC_ID)" : "=s"(xcd));
    xcd &= 7u;
    unsigned r = __hip_atomic_fetch_add(&bar[32 + xcd], 1u, __ATOMIC_RELAXED,
                                        __HIP_MEMORY_SCOPE_AGENT);
    if (r == NWRK - 1) {
      unsigned expected = 0u;
      __hip_atomic_compare_exchange_strong(&bar[40], &expected, xcd + 1u,
                                           __ATOMIC_RELAXED, __ATOMIC_RELAXED,
                                           __HIP_MEMORY_SCOPE_AGENT);
    }
    unsigned d;
    while ((d = __hip_atomic_load(&bar[40], __ATOMIC_RELAXED,
                                  __HIP_MEMORY_SCOPE_AGENT)) == 0u)
      __builtin_amdgcn_s_sleep(8);
    s_rank = (xcd == d - 1u && r < NWRK) ? (int)r : -1;
  }
  __syncthreads();
  const int rank = s_rank;
  if (rank < 0) return;

  const int wave = tid >> 6, lane = tid & 63;
  const int wgl = rank * 4 + wave;                 // 0..127
  const int mt2 = wgl >> 1;                        // 0..63
  const int nh = wgl & 1;                          // batch half
  const int mtA = 2 * mt2, mtB = mtA + 1;
  const int b0n = nh * 32 + (lane & 15);           // batch (n-tile 0)
  const int hi = lane >> 4;                        // 0..3
  const int koff = hi * 8;
  const int ulA = 8 * (wave >> 1) + hi;            // unit within WG's 16-slice
  const int ulB = ulA + 4;
  const int uA = rank * 16 + ulA;                  // global unit ids
  const int uB = rank * 16 + ulB;
  const float4 biasA = *reinterpret_cast<const float4*>(biasp + mtA * 16 + hi * 4);
  const float4 biasB = *reinterpret_cast<const float4*>(biasp + mtB * 16 + hi * 4);

  __shared__ u16 stage[64][16];                    // [batch][unit-slice]

  // preload both weight slices: 2 x 18 k-tiles x 8 bf16/lane = 144 VGPRs
  short8 wA[18], wB[18];
  {
    const u16* wa = wp + (size_t)mtA * (18 * 512) + lane * 8;
    const u16* wb = wp + (size_t)mtB * (18 * 512) + lane * 8;
    #pragma unroll
    for (int kt = 0; kt < 18; ++kt) {
      wA[kt] = *reinterpret_cast<const short8*>(wa + kt * 512);
      wB[kt] = *reinterpret_cast<const short8*>(wb + kt * 512);
    }
  }

  unsigned* slots = bar;
  float cA0 = 0.f, cA1 = 0.f, cB0 = 0.f, cB1 = 0.f;
  f32x4 accA0, accA1, accB0, accB1;

#define XPART(T) do { \
    const u16* xt_ = seq + (size_t)(T) * 4096; \
    short8 x0a = *reinterpret_cast<const short8*>(xt_ + b0n * 64 + koff); \
    short8 x1a = *reinterpret_cast<const short8*>(xt_ + (b0n + 16) * 64 + koff); \
    short8 x0b = *reinterpret_cast<const short8*>(xt_ + b0n * 64 + 32 + koff); \
    short8 x1b = *reinterpret_cast<const short8*>(xt_ + (b0n + 16) * 64 + 32 + koff); \
    f32x4 z_ = {0.f, 0.f, 0.f, 0.f}; \
    accA0 = __builtin_amdgcn_mfma_f32_16x16x32_bf16(wA[0], x0a, z_, 0, 0, 0); \
    accA1 = __builtin_amdgcn_mfma_f32_16x16x32_bf16(wA[0], x1a, z_, 0, 0, 0); \
    accB0 = __builtin_amdgcn_mfma_f32_16x16x32_bf16(wB[0], x0a, z_, 0, 0, 0); \
    accB1 = __builtin_amdgcn_mfma_f32_16x16x32_bf16(wB[0], x1a, z_, 0, 0, 0); \
    accA0 = __builtin_amdgcn_mfma_f32_16x16x32_bf16(wA[1], x0b, accA0, 0, 0, 0); \
    accA1 = __builtin_amdgcn_mfma_f32_16x16x32_bf16(wA[1], x1b, accA1, 0, 0, 0); \
    accB0 = __builtin_amdgcn_mfma_f32_16x16x32_bf16(wB[1], x0b, accB0, 0, 0, 0); \
    accB1 = __builtin_amdgcn_mfma_f32_16x16x32_bf16(wB[1], x1b, accB1, 0, 0, 0); \
  } while (0)

  XPART(0);                                        // x-part for t=0 (h(-1)=0)

  for (int t = 0; t < TP; ++t) {
    // ---- wait for h(t-1): poll 32 slots via atomic RMW at XCD L2
    if (t > 0) {
      if (wave == 0) {
        const unsigned tgt = (unsigned)t;
        for (;;) {
          unsigned v = __hip_atomic_fetch_add(&slots[lane & 31], 0u,
                                              __ATOMIC_RELAXED, __HIP_MEMORY_SCOPE_WORKGROUP);
          if (__all(v >= tgt)) break;
          __builtin_amdgcn_s_sleep(1);
        }
      }
      __syncthreads();
    }

    const u16* hc = (t & 1) ? h1buf : h0buf;
    u16* hn = (t & 1) ? h0buf : h1buf;

    // ---- issue all 32 h-fragment loads (sc0, from XCD L2), then wait once
    f32x4 hb0[16], hb1[16];
    #pragma unroll
    for (int kt = 0; kt < 16; ++kt) {
      const u16* p0 = hc + b0n * 512 + kt * 32 + koff;
      hb0[kt] = load16_sc0(p0);
      hb1[kt] = load16_sc0(p0 + 16 * 512);
    }
    asm volatile("s_waitcnt vmcnt(0)" ::: "memory");
    __builtin_amdgcn_sched_barrier(0);

    // ---- recurrent MFMAs: 16 kt x 4 (B-fragments shared across mtA/mtB)
    #pragma unroll
    for (int kt = 0; kt < 16; ++kt) {
      short8 b0 = __builtin_bit_cast(short8, hb0[kt]);
      short8 b1 = __builtin_bit_cast(short8, hb1[kt]);
      accA0 = __builtin_amdgcn_mfma_f32_16x16x32_bf16(wA[kt + 2], b0, accA0, 0, 0, 0);
      accA1 = __builtin_amdgcn_mfma_f32_16x16x32_bf16(wA[kt + 2], b1, accA1, 0, 0, 0);
      accB0 = __builtin_amdgcn_mfma_f32_16x16x32_bf16(wB[kt + 2], b0, accB0, 0, 0, 0);
      accB1 = __builtin_amdgcn_mfma_f32_16x16x32_bf16(wB[kt + 2], b1, accB1, 0, 0, 0);
    }

    // ---- gates (i,f,g,o in acc[0..3] of each lane, per mt x batch-tile)
    float iA0 = sigmoidf_(accA0[0] + biasA.x);
    float fA0 = sigmoidf_(accA0[1] + biasA.y);
    float gA0 = tanhf_(accA0[2] + biasA.z);
    float oA0 = sigmoidf_(accA0[3] + biasA.w);
    cA0 = fA0 * cA0 + iA0 * gA0;
    float hvA0 = oA0 * tanhf_(cA0);
    float iA1 = sigmoidf_(accA1[0] + biasA.x);
    float fA1 = sigmoidf_(accA1[1] + biasA.y);
    float gA1 = tanhf_(accA1[2] + biasA.z);
    float oA1 = sigmoidf_(accA1[3] + biasA.w);
    cA1 = fA1 * cA1 + iA1 * gA1;
    float hvA1 = oA1 * tanhf_(cA1);
    float iB0 = sigmoidf_(accB0[0] + biasB.x);
    float fB0 = sigmoidf_(accB0[1] + biasB.y);
    float gB0 = tanhf_(accB0[2] + biasB.z);
    float oB0 = sigmoidf_(accB0[3] + biasB.w);
    cB0 = fB0 * cB0 + iB0 * gB0;
    float hvB0 = oB0 * tanhf_(cB0);
    float iB1 = sigmoidf_(accB1[0] + biasB.x);
    float fB1 = sigmoidf_(accB1[1] + biasB.y);
    float gB1 = tanhf_(accB1[2] + biasB.z);
    float oB1 = sigmoidf_(accB1[3] + biasB.w);
    cB1 = fB1 * cB1 + iB1 * gB1;
    float hvB1 = oB1 * tanhf_(cB1);

    // ---- stage h in LDS (WG owns units [16*rank, 16*rank+16))
    stage[b0n][ulA] = f2bf(hvA0);
    stage[b0n + 16][ulA] = f2bf(hvA1);
    stage[b0n][ulB] = f2bf(hvB0);
    stage[b0n + 16][ulB] = f2bf(hvB1);
    if (t == TP - 1) {
      hfin[b0n * 512 + uA] = hvA0;
      hfin[(b0n + 16) * 512 + uA] = hvA1;
      hfin[b0n * 512 + uB] = hvB0;
      hfin[(b0n + 16) * 512 + uB] = hvB1;
    }
    __syncthreads();

    // ---- coalesced sc0 h stores: 128 threads x 16B into XCD L2
    if (tid < 128) {
      int b = tid >> 1, ch = tid & 1;
      f32x4 val = *reinterpret_cast<const f32x4*>(&stage[b][ch * 8]);
      store16_sc0(hn + b * 512 + rank * 16 + ch * 8, val);
    }
    asm volatile("s_waitcnt vmcnt(0)" ::: "memory");
    __syncthreads();                               // all waves' stores drained

    if (tid == 0)
      __hip_atomic_fetch_add(&slots[rank], 1u, __ATOMIC_RELAXED,
                             __HIP_MEMORY_SCOPE_WORKGROUP);

    // ---- x-part prefetch for t+1 (plain cached loads) overlaps others' polls
    if (t + 1 < TP) XPART(t + 1);
  }
#undef XPART
}

// ---- final linear: out[b][o] = h . lin_w[o] + lin_b[o]  (fp32)
__global__ void k_fc(const float* __restrict__ hfin, const float* __restrict__ lin_w,
                     const float* __restrict__ lin_b, float* __restrict__ out) {
  int b = blockIdx.x, o = threadIdx.x;             // 128 threads
  const float* hp = hfin + b * 512;
  const float* wq = lin_w + o * 512;
  float s = lin_b[o];
  #pragma unroll 4
  for (int j = 0; j < 512; ++j) s += hp[j] * wq[j];
  out[b * 128 + o] = s;
}

extern "C" void kernel_launch(void* const* d_in, const int* in_sizes, int n_in,
                              void* d_out, int out_size, void* d_ws, size_t ws_size,
                              hipStream_t stream) {
  const float* inX    = (const float*)d_in[0];
  const float* conv_w = (const float*)d_in[2];
  const float* conv_b = (const float*)d_in[3];
  const float* w_ih   = (const float*)d_in[4];
  const float* w_hh   = (const float*)d_in[5];
  const float* b_ih   = (const float*)d_in[6];
  const float* b_hh   = (const float*)d_in[7];
  const float* lin_w  = (const float*)d_in[8];
  const float* lin_b  = (const float*)d_in[9];
  float* out = (float*)d_out;
  char* ws = (char*)d_ws;
  u16*      wpack = (u16*)(ws + OFF_WPACK);
  u16*      seq   = (u16*)(ws + OFF_SEQ);
  float*    biasp = (float*)(ws + OFF_BIAS);
  u16*      h0b   = (u16*)(ws + OFF_H0);
  u16*      h1b   = (u16*)(ws + OFF_H1);
  float*    hfin  = (float*)(ws + OFF_HFIN);
  unsigned* bar   = (unsigned*)(ws + OFF_BAR);

  k_init<<<dim3(128), dim3(256), 0, stream>>>(b_ih, b_hh, biasp, (unsigned*)(ws + OFF_H0), bar);
  k_pack<<<dim3(4608), dim3(256), 0, stream>>>(w_ih, w_hh, wpack);
  k_conv<<<dim3(256, 64), dim3(256), 0, stream>>>(inX, conv_w, conv_b, seq);
  k_lstm<<<dim3(256), dim3(256), 0, stream>>>(seq, wpack, biasp, h0b, h1b, hfin, bar);
  k_fc<<<dim3(64), dim3(128), 0, stream>>>(hfin, lin_w, lin_b, out);
}

// Round 7
// 6773.035 us; speedup vs baseline: 1.4200x; 1.0023x over previous
//
#include <hip/hip_runtime.h>

typedef __attribute__((ext_vector_type(8))) short short8;
typedef __attribute__((ext_vector_type(4))) float f32x4;
typedef unsigned short u16;
typedef unsigned long long u64;

#define TP   1022      // conv output length = T-2
#define NWRK 32        // worker WGs (all on one XCD)

// ws layout (byte offsets, all 256-aligned)
#define OFF_WPACK   0            // 2048*576*2   = 2359296
#define OFF_SEQ     2359296      // 1022*64*64*2 = 8372224
#define OFF_BIAS    10993664     // 2048*4       = 8192
#define OFF_H0      11001856     // 64*512*2     = 65536
#define OFF_H1      11067392     // 64*512*2     = 65536
#define OFF_HFIN    11132928     // 64*512*4     = 131072
#define OFF_BAR     11264000     // cnt @0, xcdcnt[8] @32, designated @40

__device__ inline u16 f2bf(float x) {
  union { float f; unsigned u; } un; un.f = x;
  unsigned r = un.u + 0x7fffu + ((un.u >> 16) & 1u);  // RNE
  return (u16)(r >> 16);
}
__device__ inline float sigmoidf_(float x) { return 1.f / (1.f + __expf(-x)); }
__device__ inline float tanhf_(float x)    { return 2.f / (1.f + __expf(-2.f * x)) - 1.f; }

// 16B load/store that are served by the XCD-local L2 (sc0; L1 lines for h are
// capacity-evicted each step, and the L2 atomic-RMW sync provides the ordering).
__device__ inline f32x4 load16_sc0(const void* p) {
  f32x4 r;
  asm volatile("global_load_dwordx4 %0, %1, off sc0" : "=v"(r) : "v"(p) : "memory");
  return r;
}
__device__ inline void store16_sc0(void* p, f32x4 v) {
  asm volatile("global_store_dwordx4 %0, %1, off sc0" :: "v"(p), "v"(v) : "memory");
}

// ---- init: zero h buffers + barrier region, build packed bias (b_ih+b_hh, n=4j+g)
__global__ void k_init(const float* __restrict__ b_ih, const float* __restrict__ b_hh,
                       float* __restrict__ biasp, unsigned* __restrict__ hzero,
                       unsigned* __restrict__ bar) {
  int tid = blockIdx.x * 256 + threadIdx.x;
  if (tid < 32768) hzero[tid] = 0u;                 // both h bufs (131072 B)
  if (tid < 2048) {
    int j = tid >> 2, g = tid & 3;
    int row = g * 512 + j;
    biasp[tid] = b_ih[row] + b_hh[row];
  }
  if (tid < 128) bar[tid] = 0u;                     // cnt + xcdcnt + designated
}

// ---- pack W = [w_ih ; w_hh] (2048 x 576) into MFMA A-fragment order, bf16.
__global__ void k_pack(const float* __restrict__ w_ih, const float* __restrict__ w_hh,
                       u16* __restrict__ wp) {
  int idx = blockIdx.x * 256 + threadIdx.x;        // < 128*18*512 = 1179648
  int nt = idx / 9216;
  int rem = idx - nt * 9216;
  int kt = rem / 512;
  int rem2 = rem - kt * 512;
  int lane = rem2 >> 3, i = rem2 & 7;
  int n = nt * 16 + (lane & 15);
  int k = kt * 32 + (lane >> 4) * 8 + i;
  int j = n >> 2, g = n & 3;
  int row = g * 512 + j;
  float v = (k < 64) ? w_ih[row * 64 + k] : w_hh[row * 512 + (k - 64)];
  wp[idx] = f2bf(v);
}

// ---- normalize (fused) + conv1d(k=3, VALID) + relu -> seq[t][b][oc] bf16
__global__ __launch_bounds__(256) void k_conv(const float* __restrict__ inX,
                                              const float* __restrict__ conv_w,
                                              const float* __restrict__ conv_b,
                                              u16* __restrict__ seq) {
  __shared__ float xn[6][128];
  __shared__ float rn[6];
  int b = blockIdx.y;
  int t0 = blockIdx.x * 4;
  int tid = threadIdx.x;
  for (int e = tid; e < 768; e += 256) {
    int ri = e >> 7, col = e & 127;
    int t = t0 + ri;
    xn[ri][col] = (t < 1024) ? inX[((size_t)b * 1024 + t) * 128 + col] : 0.f;
  }
  __syncthreads();
  if (tid < 192) {                                 // 6 rows x 32 lanes
    int ri = tid >> 5, l32 = tid & 31;
    float4 v = *reinterpret_cast<const float4*>(&xn[ri][l32 * 4]);
    float s = v.x * v.x + v.y * v.y + v.z * v.z + v.w * v.w;
    #pragma unroll
    for (int d = 1; d < 32; d <<= 1) s += __shfl_xor(s, d, 32);
    if (l32 == 0) rn[ri] = 1.f / fmaxf(sqrtf(s), 1e-12f);
  }
  __syncthreads();
  for (int e = tid; e < 768; e += 256) {
    int ri = e >> 7, col = e & 127;
    xn[ri][col] *= rn[ri];
  }
  __syncthreads();
  int oc = tid & 63, ty = tid >> 6;
  int t = t0 + ty;
  if (t < TP) {
    const float* wr = conv_w + oc * 384;           // (OC, IN, 3) row-major
    float s = conv_b[oc];
    #pragma unroll 4
    for (int i = 0; i < 128; ++i) {
      s += wr[i * 3 + 0] * xn[ty + 0][i]
         + wr[i * 3 + 1] * xn[ty + 1][i]
         + wr[i * 3 + 2] * xn[ty + 2][i];
    }
    s = fmaxf(s, 0.f);
    seq[((size_t)t * 64 + b) * 64 + oc] = f2bf(s);
  }
}

// ---- persistent LSTM on ONE XCD. 256 WGs launched; one XCD self-designates;
// its 32 ranked WGs run the recurrence. h exchange: sc0 16B loads/stores via
// XCD L2. Sync: SINGLE counter, atomic RMW at L2 (1 RMW per WG per poll iter,
// 1 per WG per signal) — visibility hardware-guaranteed, no RMW storm.
__global__ __launch_bounds__(256, 1) void k_lstm(const u16* __restrict__ seq,
                                                 const u16* __restrict__ wp,
                                                 const float* __restrict__ biasp,
                                                 u16* h0buf, u16* h1buf,
                                                 float* __restrict__ hfin,
                                                 unsigned* bar) {
  const int tid = threadIdx.x;
  __shared__ int s_rank;

  // ---- XCD self-designation (setup only; agent-scope atomics via MALL)
  if (tid == 0) {
    unsigned xcd;
    asm volatile("s_getreg_b32 %0, hwreg(HW_REG_XCC_ID)" : "=s"(xcd));
    xcd &= 7u;
    unsigned r = __hip_atomic_fetch_add(&bar[8 + xcd], 1u, __ATOMIC_RELAXED,
                                        __HIP_MEMORY_SCOPE_AGENT);
    if (r == NWRK - 1) {
      unsigned expected = 0u;
      __hip_atomic_compare_exchange_strong(&bar[16], &expected, xcd + 1u,
                                           __ATOMIC_RELAXED, __ATOMIC_RELAXED,
                                           __HIP_MEMORY_SCOPE_AGENT);
    }
    unsigned d;
    while ((d = __hip_atomic_load(&bar[16], __ATOMIC_RELAXED,
                                  __HIP_MEMORY_SCOPE_AGENT)) == 0u)
      __builtin_amdgcn_s_sleep(8);
    s_rank = (xcd == d - 1u && r < NWRK) ? (int)r : -1;
  }
  __syncthreads();
  const int rank = s_rank;
  if (rank < 0) return;

  const int wave = tid >> 6, lane = tid & 63;
  const int wgl = rank * 4 + wave;                 // 0..127
  const int mt2 = wgl >> 1;                        // 0..63
  const int nh = wgl & 1;                          // batch half
  const int mtA = 2 * mt2, mtB = mtA + 1;
  const int b0n = nh * 32 + (lane & 15);           // batch (n-tile 0)
  const int hi = lane >> 4;                        // 0..3
  const int koff = hi * 8;
  const int ulA = 8 * (wave >> 1) + hi;            // unit within WG's 16-slice
  const int ulB = ulA + 4;
  const int uA = rank * 16 + ulA;                  // global unit ids
  const int uB = rank * 16 + ulB;
  const float4 biasA = *reinterpret_cast<const float4*>(biasp + mtA * 16 + hi * 4);
  const float4 biasB = *reinterpret_cast<const float4*>(biasp + mtB * 16 + hi * 4);

  __shared__ u16 stage[64][16];                    // [batch][unit-slice]

  // preload both weight slices: 2 x 18 k-tiles x 8 bf16/lane = 144 VGPRs
  short8 wA[18], wB[18];
  {
    const u16* wa = wp + (size_t)mtA * (18 * 512) + lane * 8;
    const u16* wb = wp + (size_t)mtB * (18 * 512) + lane * 8;
    #pragma unroll
    for (int kt = 0; kt < 18; ++kt) {
      wA[kt] = *reinterpret_cast<const short8*>(wa + kt * 512);
      wB[kt] = *reinterpret_cast<const short8*>(wb + kt * 512);
    }
  }

  unsigned* cnt = bar;                             // single sync counter
  float cA0 = 0.f, cA1 = 0.f, cB0 = 0.f, cB1 = 0.f;
  f32x4 accA0, accA1, accB0, accB1;

#define XPART(T) do { \
    const u16* xt_ = seq + (size_t)(T) * 4096; \
    short8 x0a = *reinterpret_cast<const short8*>(xt_ + b0n * 64 + koff); \
    short8 x1a = *reinterpret_cast<const short8*>(xt_ + (b0n + 16) * 64 + koff); \
    short8 x0b = *reinterpret_cast<const short8*>(xt_ + b0n * 64 + 32 + koff); \
    short8 x1b = *reinterpret_cast<const short8*>(xt_ + (b0n + 16) * 64 + 32 + koff); \
    f32x4 z_ = {0.f, 0.f, 0.f, 0.f}; \
    accA0 = __builtin_amdgcn_mfma_f32_16x16x32_bf16(wA[0], x0a, z_, 0, 0, 0); \
    accA1 = __builtin_amdgcn_mfma_f32_16x16x32_bf16(wA[0], x1a, z_, 0, 0, 0); \
    accB0 = __builtin_amdgcn_mfma_f32_16x16x32_bf16(wB[0], x0a, z_, 0, 0, 0); \
    accB1 = __builtin_amdgcn_mfma_f32_16x16x32_bf16(wB[0], x1a, z_, 0, 0, 0); \
    accA0 = __builtin_amdgcn_mfma_f32_16x16x32_bf16(wA[1], x0b, accA0, 0, 0, 0); \
    accA1 = __builtin_amdgcn_mfma_f32_16x16x32_bf16(wA[1], x1b, accA1, 0, 0, 0); \
    accB0 = __builtin_amdgcn_mfma_f32_16x16x32_bf16(wB[1], x0b, accB0, 0, 0, 0); \
    accB1 = __builtin_amdgcn_mfma_f32_16x16x32_bf16(wB[1], x1b, accB1, 0, 0, 0); \
  } while (0)

  XPART(0);                                        // x-part for t=0 (h(-1)=0)

  for (int t = 0; t < TP; ++t) {
    // ---- wait for h(t-1): ONE RMW per WG per poll iteration at the XCD L2
    if (t > 0) {
      if (tid == 0) {
        const unsigned tgt = (unsigned)(NWRK * t);
        for (;;) {
          unsigned v = __hip_atomic_fetch_add(cnt, 0u, __ATOMIC_RELAXED,
                                              __HIP_MEMORY_SCOPE_WORKGROUP);
          if (v >= tgt) break;
          __builtin_amdgcn_s_sleep(1);
        }
      }
      __syncthreads();
    }

    const u16* hc = (t & 1) ? h1buf : h0buf;
    u16* hn = (t & 1) ? h0buf : h1buf;

    // ---- issue all 32 h-fragment loads (sc0, from XCD L2), then wait once
    f32x4 hb0[16], hb1[16];
    #pragma unroll
    for (int kt = 0; kt < 16; ++kt) {
      const u16* p0 = hc + b0n * 512 + kt * 32 + koff;
      hb0[kt] = load16_sc0(p0);
      hb1[kt] = load16_sc0(p0 + 16 * 512);
    }
    asm volatile("s_waitcnt vmcnt(0)" ::: "memory");
    __builtin_amdgcn_sched_barrier(0);

    // ---- recurrent MFMAs: 16 kt x 4 (B-fragments shared across mtA/mtB)
    #pragma unroll
    for (int kt = 0; kt < 16; ++kt) {
      short8 b0 = __builtin_bit_cast(short8, hb0[kt]);
      short8 b1 = __builtin_bit_cast(short8, hb1[kt]);
      accA0 = __builtin_amdgcn_mfma_f32_16x16x32_bf16(wA[kt + 2], b0, accA0, 0, 0, 0);
      accA1 = __builtin_amdgcn_mfma_f32_16x16x32_bf16(wA[kt + 2], b1, accA1, 0, 0, 0);
      accB0 = __builtin_amdgcn_mfma_f32_16x16x32_bf16(wB[kt + 2], b0, accB0, 0, 0, 0);
      accB1 = __builtin_amdgcn_mfma_f32_16x16x32_bf16(wB[kt + 2], b1, accB1, 0, 0, 0);
    }

    // ---- gates (i,f,g,o in acc[0..3] of each lane, per mt x batch-tile)
    float iA0 = sigmoidf_(accA0[0] + biasA.x);
    float fA0 = sigmoidf_(accA0[1] + biasA.y);
    float gA0 = tanhf_(accA0[2] + biasA.z);
    float oA0 = sigmoidf_(accA0[3] + biasA.w);
    cA0 = fA0 * cA0 + iA0 * gA0;
    float hvA0 = oA0 * tanhf_(cA0);
    float iA1 = sigmoidf_(accA1[0] + biasA.x);
    float fA1 = sigmoidf_(accA1[1] + biasA.y);
    float gA1 = tanhf_(accA1[2] + biasA.z);
    float oA1 = sigmoidf_(accA1[3] + biasA.w);
    cA1 = fA1 * cA1 + iA1 * gA1;
    float hvA1 = oA1 * tanhf_(cA1);
    float iB0 = sigmoidf_(accB0[0] + biasB.x);
    float fB0 = sigmoidf_(accB0[1] + biasB.y);
    float gB0 = tanhf_(accB0[2] + biasB.z);
    float oB0 = sigmoidf_(accB0[3] + biasB.w);
    cB0 = fB0 * cB0 + iB0 * gB0;
    float hvB0 = oB0 * tanhf_(cB0);
    float iB1 = sigmoidf_(accB1[0] + biasB.x);
    float fB1 = sigmoidf_(accB1[1] + biasB.y);
    float gB1 = tanhf_(accB1[2] + biasB.z);
    float oB1 = sigmoidf_(accB1[3] + biasB.w);
    cB1 = fB1 * cB1 + iB1 * gB1;
    float hvB1 = oB1 * tanhf_(cB1);

    // ---- stage h in LDS (WG owns units [16*rank, 16*rank+16))
    stage[b0n][ulA] = f2bf(hvA0);
    stage[b0n + 16][ulA] = f2bf(hvA1);
    stage[b0n][ulB] = f2bf(hvB0);
    stage[b0n + 16][ulB] = f2bf(hvB1);
    if (t == TP - 1) {
      hfin[b0n * 512 + uA] = hvA0;
      hfin[(b0n + 16) * 512 + uA] = hvA1;
      hfin[b0n * 512 + uB] = hvB0;
      hfin[(b0n + 16) * 512 + uB] = hvB1;
    }
    __syncthreads();

    // ---- coalesced sc0 h stores: 128 threads x 16B into XCD L2
    if (tid < 128) {
      int b = tid >> 1, ch = tid & 1;
      f32x4 val = *reinterpret_cast<const f32x4*>(&stage[b][ch * 8]);
      store16_sc0(hn + b * 512 + rank * 16 + ch * 8, val);
    }
    asm volatile("s_waitcnt vmcnt(0)" ::: "memory");
    __syncthreads();                               // all waves' stores drained

    // ---- signal: ONE atomic RMW per WG (L2 execution point = visibility)
    if (tid == 0)
      __hip_atomic_fetch_add(cnt, 1u, __ATOMIC_RELAXED, __HIP_MEMORY_SCOPE_WORKGROUP);

    // ---- x-part prefetch for t+1 (plain cached loads) overlaps others' polls
    if (t + 1 < TP) XPART(t + 1);
  }
#undef XPART
}

// ---- final linear: out[b][o] = h . lin_w[o] + lin_b[o]  (fp32)
__global__ void k_fc(const float* __restrict__ hfin, const float* __restrict__ lin_w,
                     const float* __restrict__ lin_b, float* __restrict__ out) {
  int b = blockIdx.x, o = threadIdx.x;             // 128 threads
  const float* hp = hfin + b * 512;
  const float* wq = lin_w + o * 512;
  float s = lin_b[o];
  #pragma unroll 4
  for (int j = 0; j < 512; ++j) s += hp[j] * wq[j];
  out[b * 128 + o] = s;
}

extern "C" void kernel_launch(void* const* d_in, const int* in_sizes, int n_in,
                              void* d_out, int out_size, void* d_ws, size_t ws_size,
                              hipStream_t stream) {
  const float* inX    = (const float*)d_in[0];
  const float* conv_w = (const float*)d_in[2];
  const float* conv_b = (const float*)d_in[3];
  const float* w_ih   = (const float*)d_in[4];
  const float* w_hh   = (const float*)d_in[5];
  const float* b_ih   = (const float*)d_in[6];
  const float* b_hh   = (const float*)d_in[7];
  const float* lin_w  = (const float*)d_in[8];
  const float* lin_b  = (const float*)d_in[9];
  float* out = (float*)d_out;
  char* ws = (char*)d_ws;
  u16*      wpack = (u16*)(ws + OFF_WPACK);
  u16*      seq   = (u16*)(ws + OFF_SEQ);
  float*    biasp = (float*)(ws + OFF_BIAS);
  u16*      h0b   = (u16*)(ws + OFF_H0);
  u16*      h1b   = (u16*)(ws + OFF_H1);
  float*    hfin  = (float*)(ws + OFF_HFIN);
  unsigned* bar   = (unsigned*)(ws + OFF_BAR);

  k_init<<<dim3(128), dim3(256), 0, stream>>>(b_ih, b_hh, biasp, (unsigned*)(ws + OFF_H0), bar);
  k_pack<<<dim3(4608), dim3(256), 0, stream>>>(w_ih, w_hh, wpack);
  k_conv<<<dim3(256, 64), dim3(256), 0, stream>>>(inX, conv_w, conv_b, seq);
  k_lstm<<<dim3(256), dim3(256), 0, stream>>>(seq, wpack, biasp, h0b, h1b, hfin, bar);
  k_fc<<<dim3(64), dim3(128), 0, stream>>>(hfin, lin_w, lin_b, out);
}

// Round 8
// 6660.096 us; speedup vs baseline: 1.4441x; 1.0170x over previous
//
#include <hip/hip_runtime.h>

typedef __attribute__((ext_vector_type(8))) short short8;
typedef __attribute__((ext_vector_type(4))) float f32x4;
typedef unsigned short u16;
typedef unsigned long long u64;

#define TP   1022      // conv output length = T-2
#define NWRK 32        // worker WGs (all on one XCD)

// ws layout (byte offsets, all 256-aligned)
#define OFF_WPACK   0            // 2048*576*2   = 2359296
#define OFF_SEQ     2359296      // 1022*64*64*2 = 8372224
#define OFF_BIAS    10993664     // 2048*4       = 8192
#define OFF_H0      11001856     // 64*512*2     = 65536
#define OFF_H1      11067392     // 64*512*2     = 65536
#define OFF_HFIN    11132928     // 64*512*4     = 131072
#define OFF_BAR     11264000     // cnt @0, xcdcnt @+32B, designated @+64B, done @+256B

__device__ inline u16 f2bf(float x) {
  union { float f; unsigned u; } un; un.f = x;
  unsigned r = un.u + 0x7fffu + ((un.u >> 16) & 1u);  // RNE
  return (u16)(r >> 16);
}
__device__ inline float sigmoidf_(float x) { return 1.f / (1.f + __expf(-x)); }
__device__ inline float tanhf_(float x)    { return 2.f / (1.f + __expf(-2.f * x)) - 1.f; }

// 16B load/store that are served by the XCD-local L2 (sc0; L1 lines for h are
// capacity-evicted each step, and the L2 atomic-RMW sync provides the ordering).
__device__ inline f32x4 load16_sc0(const void* p) {
  f32x4 r;
  asm volatile("global_load_dwordx4 %0, %1, off sc0" : "=v"(r) : "v"(p) : "memory");
  return r;
}
__device__ inline void store16_sc0(void* p, f32x4 v) {
  asm volatile("global_store_dwordx4 %0, %1, off sc0" :: "v"(p), "v"(v) : "memory");
}

// ---- init: zero h buffers + barrier region, build packed bias (b_ih+b_hh, n=4j+g)
__global__ void k_init(const float* __restrict__ b_ih, const float* __restrict__ b_hh,
                       float* __restrict__ biasp, unsigned* __restrict__ hzero,
                       unsigned* __restrict__ bar) {
  int tid = blockIdx.x * 256 + threadIdx.x;
  if (tid < 32768) hzero[tid] = 0u;                 // both h bufs (131072 B)
  if (tid < 2048) {
    int j = tid >> 2, g = tid & 3;
    int row = g * 512 + j;
    biasp[tid] = b_ih[row] + b_hh[row];
  }
  if (tid < 128) bar[tid] = 0u;                     // cnt + xcdcnt + designated + done
}

// ---- pack W = [w_ih ; w_hh] (2048 x 576) into MFMA A-fragment order, bf16.
__global__ void k_pack(const float* __restrict__ w_ih, const float* __restrict__ w_hh,
                       u16* __restrict__ wp) {
  int idx = blockIdx.x * 256 + threadIdx.x;        // < 128*18*512 = 1179648
  int nt = idx / 9216;
  int rem = idx - nt * 9216;
  int kt = rem / 512;
  int rem2 = rem - kt * 512;
  int lane = rem2 >> 3, i = rem2 & 7;
  int n = nt * 16 + (lane & 15);
  int k = kt * 32 + (lane >> 4) * 8 + i;
  int j = n >> 2, g = n & 3;
  int row = g * 512 + j;
  float v = (k < 64) ? w_ih[row * 64 + k] : w_hh[row * 512 + (k - 64)];
  wp[idx] = f2bf(v);
}

// ---- normalize (fused) + conv1d(k=3, VALID) + relu -> seq[t][b][oc] bf16
__global__ __launch_bounds__(256) void k_conv(const float* __restrict__ inX,
                                              const float* __restrict__ conv_w,
                                              const float* __restrict__ conv_b,
                                              u16* __restrict__ seq) {
  __shared__ float xn[6][128];
  __shared__ float rn[6];
  int b = blockIdx.y;
  int t0 = blockIdx.x * 4;
  int tid = threadIdx.x;
  for (int e = tid; e < 768; e += 256) {
    int ri = e >> 7, col = e & 127;
    int t = t0 + ri;
    xn[ri][col] = (t < 1024) ? inX[((size_t)b * 1024 + t) * 128 + col] : 0.f;
  }
  __syncthreads();
  if (tid < 192) {                                 // 6 rows x 32 lanes
    int ri = tid >> 5, l32 = tid & 31;
    float4 v = *reinterpret_cast<const float4*>(&xn[ri][l32 * 4]);
    float s = v.x * v.x + v.y * v.y + v.z * v.z + v.w * v.w;
    #pragma unroll
    for (int d = 1; d < 32; d <<= 1) s += __shfl_xor(s, d, 32);
    if (l32 == 0) rn[ri] = 1.f / fmaxf(sqrtf(s), 1e-12f);
  }
  __syncthreads();
  for (int e = tid; e < 768; e += 256) {
    int ri = e >> 7, col = e & 127;
    xn[ri][col] *= rn[ri];
  }
  __syncthreads();
  int oc = tid & 63, ty = tid >> 6;
  int t = t0 + ty;
  if (t < TP) {
    const float* wr = conv_w + oc * 384;           // (OC, IN, 3) row-major
    float s = conv_b[oc];
    #pragma unroll 4
    for (int i = 0; i < 128; ++i) {
      s += wr[i * 3 + 0] * xn[ty + 0][i]
         + wr[i * 3 + 1] * xn[ty + 1][i]
         + wr[i * 3 + 2] * xn[ty + 2][i];
    }
    s = fmaxf(s, 0.f);
    seq[((size_t)t * 64 + b) * 64 + oc] = f2bf(s);
  }
}

// ---- persistent LSTM on ONE XCD (workers byte-identical to round 7).
// NEW: the 224 non-designated WGs run a low-power clock-keeper spin (dependent
// FMA chain, ~25% issue duty) so the DVFS governor sees ~100% GUI-active and
// holds boost clocks, instead of floor-clocking this 1%-utilization kernel.
__global__ __launch_bounds__(256, 1) void k_lstm(const u16* __restrict__ seq,
                                                 const u16* __restrict__ wp,
                                                 const float* __restrict__ biasp,
                                                 u16* h0buf, u16* h1buf,
                                                 float* __restrict__ hfin,
                                                 unsigned* bar) {
  const int tid = threadIdx.x;
  __shared__ int s_rank;

  // ---- XCD self-designation (setup only; agent-scope atomics via MALL)
  if (tid == 0) {
    unsigned xcd;
    asm volatile("s_getreg_b32 %0, hwreg(HW_REG_XCC_ID)" : "=s"(xcd));
    xcd &= 7u;
    unsigned r = __hip_atomic_fetch_add(&bar[8 + xcd], 1u, __ATOMIC_RELAXED,
                                        __HIP_MEMORY_SCOPE_AGENT);
    if (r == NWRK - 1) {
      unsigned expected = 0u;
      __hip_atomic_compare_exchange_strong(&bar[16], &expected, xcd + 1u,
                                           __ATOMIC_RELAXED, __ATOMIC_RELAXED,
                                           __HIP_MEMORY_SCOPE_AGENT);
    }
    unsigned d;
    while ((d = __hip_atomic_load(&bar[16], __ATOMIC_RELAXED,
                                  __HIP_MEMORY_SCOPE_AGENT)) == 0u)
      __builtin_amdgcn_s_sleep(8);
    s_rank = (xcd == d - 1u && r < NWRK) ? (int)r : -1;
  }
  __syncthreads();
  const int rank = s_rank;

  if (rank < 0) {
    // ---- clock keeper: dependent-FMA spin until all workers signal done.
    // done counter @ bar[64] (separate 256B line from cnt; MALL-scope RMW).
    const int lane_ = tid & 63;
    float x = (float)tid + 1.0f;
    unsigned d = 0;
    do {
      #pragma unroll
      for (int i = 0; i < 1024; ++i) x = __builtin_fmaf(x, 1.0000001f, 1.0e-30f);
      asm volatile("" :: "v"(x));                  // keep the chain live (no DCE)
      if (lane_ == 0)
        d = __hip_atomic_fetch_add(&bar[64], 0u, __ATOMIC_RELAXED,
                                   __HIP_MEMORY_SCOPE_AGENT);
      d = __shfl(d, 0);
    } while (d < NWRK);
    return;
  }

  const int wave = tid >> 6, lane = tid & 63;
  const int wgl = rank * 4 + wave;                 // 0..127
  const int mt2 = wgl >> 1;                        // 0..63
  const int nh = wgl & 1;                          // batch half
  const int mtA = 2 * mt2, mtB = mtA + 1;
  const int b0n = nh * 32 + (lane & 15);           // batch (n-tile 0)
  const int hi = lane >> 4;                        // 0..3
  const int koff = hi * 8;
  const int ulA = 8 * (wave >> 1) + hi;            // unit within WG's 16-slice
  const int ulB = ulA + 4;
  const int uA = rank * 16 + ulA;                  // global unit ids
  const int uB = rank * 16 + ulB;
  const float4 biasA = *reinterpret_cast<const float4*>(biasp + mtA * 16 + hi * 4);
  const float4 biasB = *reinterpret_cast<const float4*>(biasp + mtB * 16 + hi * 4);

  __shared__ u16 stage[64][16];                    // [batch][unit-slice]

  // preload both weight slices: 2 x 18 k-tiles x 8 bf16/lane = 144 VGPRs
  short8 wA[18], wB[18];
  {
    const u16* wa = wp + (size_t)mtA * (18 * 512) + lane * 8;
    const u16* wb = wp + (size_t)mtB * (18 * 512) + lane * 8;
    #pragma unroll
    for (int kt = 0; kt < 18; ++kt) {
      wA[kt] = *reinterpret_cast<const short8*>(wa + kt * 512);
      wB[kt] = *reinterpret_cast<const short8*>(wb + kt * 512);
    }
  }

  unsigned* cnt = bar;                             // single sync counter
  float cA0 = 0.f, cA1 = 0.f, cB0 = 0.f, cB1 = 0.f;
  f32x4 accA0, accA1, accB0, accB1;

#define XPART(T) do { \
    const u16* xt_ = seq + (size_t)(T) * 4096; \
    short8 x0a = *reinterpret_cast<const short8*>(xt_ + b0n * 64 + koff); \
    short8 x1a = *reinterpret_cast<const short8*>(xt_ + (b0n + 16) * 64 + koff); \
    short8 x0b = *reinterpret_cast<const short8*>(xt_ + b0n * 64 + 32 + koff); \
    short8 x1b = *reinterpret_cast<const short8*>(xt_ + (b0n + 16) * 64 + 32 + koff); \
    f32x4 z_ = {0.f, 0.f, 0.f, 0.f}; \
    accA0 = __builtin_amdgcn_mfma_f32_16x16x32_bf16(wA[0], x0a, z_, 0, 0, 0); \
    accA1 = __builtin_amdgcn_mfma_f32_16x16x32_bf16(wA[0], x1a, z_, 0, 0, 0); \
    accB0 = __builtin_amdgcn_mfma_f32_16x16x32_bf16(wB[0], x0a, z_, 0, 0, 0); \
    accB1 = __builtin_amdgcn_mfma_f32_16x16x32_bf16(wB[0], x1a, z_, 0, 0, 0); \
    accA0 = __builtin_amdgcn_mfma_f32_16x16x32_bf16(wA[1], x0b, accA0, 0, 0, 0); \
    accA1 = __builtin_amdgcn_mfma_f32_16x16x32_bf16(wA[1], x1b, accA1, 0, 0, 0); \
    accB0 = __builtin_amdgcn_mfma_f32_16x16x32_bf16(wB[1], x0b, accB0, 0, 0, 0); \
    accB1 = __builtin_amdgcn_mfma_f32_16x16x32_bf16(wB[1], x1b, accB1, 0, 0, 0); \
  } while (0)

  XPART(0);                                        // x-part for t=0 (h(-1)=0)

  for (int t = 0; t < TP; ++t) {
    // ---- wait for h(t-1): ONE RMW per WG per poll iteration at the XCD L2
    if (t > 0) {
      if (tid == 0) {
        const unsigned tgt = (unsigned)(NWRK * t);
        for (;;) {
          unsigned v = __hip_atomic_fetch_add(cnt, 0u, __ATOMIC_RELAXED,
                                              __HIP_MEMORY_SCOPE_WORKGROUP);
          if (v >= tgt) break;
          __builtin_amdgcn_s_sleep(1);
        }
      }
      __syncthreads();
    }

    const u16* hc = (t & 1) ? h1buf : h0buf;
    u16* hn = (t & 1) ? h0buf : h1buf;

    // ---- issue all 32 h-fragment loads (sc0, from XCD L2), then wait once
    f32x4 hb0[16], hb1[16];
    #pragma unroll
    for (int kt = 0; kt < 16; ++kt) {
      const u16* p0 = hc + b0n * 512 + kt * 32 + koff;
      hb0[kt] = load16_sc0(p0);
      hb1[kt] = load16_sc0(p0 + 16 * 512);
    }
    asm volatile("s_waitcnt vmcnt(0)" ::: "memory");
    __builtin_amdgcn_sched_barrier(0);

    // ---- recurrent MFMAs: 16 kt x 4 (B-fragments shared across mtA/mtB)
    #pragma unroll
    for (int kt = 0; kt < 16; ++kt) {
      short8 b0 = __builtin_bit_cast(short8, hb0[kt]);
      short8 b1 = __builtin_bit_cast(short8, hb1[kt]);
      accA0 = __builtin_amdgcn_mfma_f32_16x16x32_bf16(wA[kt + 2], b0, accA0, 0, 0, 0);
      accA1 = __builtin_amdgcn_mfma_f32_16x16x32_bf16(wA[kt + 2], b1, accA1, 0, 0, 0);
      accB0 = __builtin_amdgcn_mfma_f32_16x16x32_bf16(wB[kt + 2], b0, accB0, 0, 0, 0);
      accB1 = __builtin_amdgcn_mfma_f32_16x16x32_bf16(wB[kt + 2], b1, accB1, 0, 0, 0);
    }

    // ---- gates (i,f,g,o in acc[0..3] of each lane, per mt x batch-tile)
    float iA0 = sigmoidf_(accA0[0] + biasA.x);
    float fA0 = sigmoidf_(accA0[1] + biasA.y);
    float gA0 = tanhf_(accA0[2] + biasA.z);
    float oA0 = sigmoidf_(accA0[3] + biasA.w);
    cA0 = fA0 * cA0 + iA0 * gA0;
    float hvA0 = oA0 * tanhf_(cA0);
    float iA1 = sigmoidf_(accA1[0] + biasA.x);
    float fA1 = sigmoidf_(accA1[1] + biasA.y);
    float gA1 = tanhf_(accA1[2] + biasA.z);
    float oA1 = sigmoidf_(accA1[3] + biasA.w);
    cA1 = fA1 * cA1 + iA1 * gA1;
    float hvA1 = oA1 * tanhf_(cA1);
    float iB0 = sigmoidf_(accB0[0] + biasB.x);
    float fB0 = sigmoidf_(accB0[1] + biasB.y);
    float gB0 = tanhf_(accB0[2] + biasB.z);
    float oB0 = sigmoidf_(accB0[3] + biasB.w);
    cB0 = fB0 * cB0 + iB0 * gB0;
    float hvB0 = oB0 * tanhf_(cB0);
    float iB1 = sigmoidf_(accB1[0] + biasB.x);
    float fB1 = sigmoidf_(accB1[1] + biasB.y);
    float gB1 = tanhf_(accB1[2] + biasB.z);
    float oB1 = sigmoidf_(accB1[3] + biasB.w);
    cB1 = fB1 * cB1 + iB1 * gB1;
    float hvB1 = oB1 * tanhf_(cB1);

    // ---- stage h in LDS (WG owns units [16*rank, 16*rank+16))
    stage[b0n][ulA] = f2bf(hvA0);
    stage[b0n + 16][ulA] = f2bf(hvA1);
    stage[b0n][ulB] = f2bf(hvB0);
    stage[b0n + 16][ulB] = f2bf(hvB1);
    if (t == TP - 1) {
      hfin[b0n * 512 + uA] = hvA0;
      hfin[(b0n + 16) * 512 + uA] = hvA1;
      hfin[b0n * 512 + uB] = hvB0;
      hfin[(b0n + 16) * 512 + uB] = hvB1;
    }
    __syncthreads();

    // ---- coalesced sc0 h stores: 128 threads x 16B into XCD L2
    if (tid < 128) {
      int b = tid >> 1, ch = tid & 1;
      f32x4 val = *reinterpret_cast<const f32x4*>(&stage[b][ch * 8]);
      store16_sc0(hn + b * 512 + rank * 16 + ch * 8, val);
    }
    asm volatile("s_waitcnt vmcnt(0)" ::: "memory");
    __syncthreads();                               // all waves' stores drained

    // ---- signal: ONE atomic RMW per WG (L2 execution point = visibility)
    if (tid == 0)
      __hip_atomic_fetch_add(cnt, 1u, __ATOMIC_RELAXED, __HIP_MEMORY_SCOPE_WORKGROUP);

    // ---- x-part prefetch for t+1 (plain cached loads) overlaps others' polls
    if (t + 1 < TP) XPART(t + 1);
  }
#undef XPART

  // ---- tell the clock keepers we're done (MALL-scope RMW, cross-XCD visible)
  if (tid == 0)
    __hip_atomic_fetch_add(&bar[64], 1u, __ATOMIC_RELAXED, __HIP_MEMORY_SCOPE_AGENT);
}

// ---- final linear: out[b][o] = h . lin_w[o] + lin_b[o]  (fp32)
__global__ void k_fc(const float* __restrict__ hfin, const float* __restrict__ lin_w,
                     const float* __restrict__ lin_b, float* __restrict__ out) {
  int b = blockIdx.x, o = threadIdx.x;             // 128 threads
  const float* hp = hfin + b * 512;
  const float* wq = lin_w + o * 512;
  float s = lin_b[o];
  #pragma unroll 4
  for (int j = 0; j < 512; ++j) s += hp[j] * wq[j];
  out[b * 128 + o] = s;
}

extern "C" void kernel_launch(void* const* d_in, const int* in_sizes, int n_in,
                              void* d_out, int out_size, void* d_ws, size_t ws_size,
                              hipStream_t stream) {
  const float* inX    = (const float*)d_in[0];
  const float* conv_w = (const float*)d_in[2];
  const float* conv_b = (const float*)d_in[3];
  const float* w_ih   = (const float*)d_in[4];
  const float* w_hh   = (const float*)d_in[5];
  const float* b_ih   = (const float*)d_in[6];
  const float* b_hh   = (const float*)d_in[7];
  const float* lin_w  = (const float*)d_in[8];
  const float* lin_b  = (const float*)d_in[9];
  float* out = (float*)d_out;
  char* ws = (char*)d_ws;
  u16*      wpack = (u16*)(ws + OFF_WPACK);
  u16*      seq   = (u16*)(ws + OFF_SEQ);
  float*    biasp = (float*)(ws + OFF_BIAS);
  u16*      h0b   = (u16*)(ws + OFF_H0);
  u16*      h1b   = (u16*)(ws + OFF_H1);
  float*    hfin  = (float*)(ws + OFF_HFIN);
  unsigned* bar   = (unsigned*)(ws + OFF_BAR);

  k_init<<<dim3(128), dim3(256), 0, stream>>>(b_ih, b_hh, biasp, (unsigned*)(ws + OFF_H0), bar);
  k_pack<<<dim3(4608), dim3(256), 0, stream>>>(w_ih, w_hh, wpack);
  k_conv<<<dim3(256, 64), dim3(256), 0, stream>>>(inX, conv_w, conv_b, seq);
  k_lstm<<<dim3(256), dim3(256), 0, stream>>>(seq, wpack, biasp, h0b, h1b, hfin, bar);
  k_fc<<<dim3(64), dim3(128), 0, stream>>>(hfin, lin_w, lin_b, out);
}

// Round 10
// 6650.879 us; speedup vs baseline: 1.4461x; 1.0014x over previous
//
#include <hip/hip_runtime.h>

typedef __attribute__((ext_vector_type(8))) short short8;
typedef __attribute__((ext_vector_type(4))) float f32x4;
typedef unsigned short u16;
typedef unsigned long long u64;

#define TP   1022      // conv output length = T-2
#define NWRK 32        // worker WGs (all on one XCD)

// ws layout (byte offsets, all 256-aligned)
#define OFF_WPACK   0            // 2048*576*2   = 2359296
#define OFF_SEQ     2359296      // 1022*64*64*2 = 8372224
#define OFF_BIAS    10993664     // 2048*4       = 8192
#define OFF_H0      11001856     // 64*512*2     = 65536
#define OFF_H1      11067392     // 64*512*2     = 65536
#define OFF_HFIN    11132928     // 64*512*4     = 131072
#define OFF_BAR     11264000     // cnt @0, xcdcnt @+32B, designated @+64B, done @+256B

__device__ inline u16 f2bf(float x) {
  union { float f; unsigned u; } un; un.f = x;
  unsigned r = un.u + 0x7fffu + ((un.u >> 16) & 1u);  // RNE
  return (u16)(r >> 16);
}
__device__ inline float sigmoidf_(float x) { return 1.f / (1.f + __expf(-x)); }
__device__ inline float tanhf_(float x)    { return 2.f / (1.f + __expf(-2.f * x)) - 1.f; }

// 16B load/store served by the XCD-local L2 (sc0; h lines are L1-capacity-evicted
// each step, and the atomic-RMW sync at L2 provides ordering/visibility).
__device__ inline f32x4 load16_sc0(const void* p) {
  f32x4 r;
  asm volatile("global_load_dwordx4 %0, %1, off sc0" : "=v"(r) : "v"(p) : "memory");
  return r;
}
__device__ inline void store16_sc0(void* p, f32x4 v) {
  asm volatile("global_store_dwordx4 %0, %1, off sc0" :: "v"(p), "v"(v) : "memory");
}

// ---- init: zero h buffers + barrier region, build packed bias (b_ih+b_hh, n=4j+g)
__global__ void k_init(const float* __restrict__ b_ih, const float* __restrict__ b_hh,
                       float* __restrict__ biasp, unsigned* __restrict__ hzero,
                       unsigned* __restrict__ bar) {
  int tid = blockIdx.x * 256 + threadIdx.x;
  if (tid < 32768) hzero[tid] = 0u;                 // both h bufs (131072 B)
  if (tid < 2048) {
    int j = tid >> 2, g = tid & 3;
    int row = g * 512 + j;
    biasp[tid] = b_ih[row] + b_hh[row];
  }
  if (tid < 128) bar[tid] = 0u;                     // cnt + xcdcnt + designated + done
}

// ---- pack W = [w_ih ; w_hh] (2048 x 576) into MFMA A-fragment order, bf16.
__global__ void k_pack(const float* __restrict__ w_ih, const float* __restrict__ w_hh,
                       u16* __restrict__ wp) {
  int idx = blockIdx.x * 256 + threadIdx.x;        // < 128*18*512 = 1179648
  int nt = idx / 9216;
  int rem = idx - nt * 9216;
  int kt = rem / 512;
  int rem2 = rem - kt * 512;
  int lane = rem2 >> 3, i = rem2 & 7;
  int n = nt * 16 + (lane & 15);
  int k = kt * 32 + (lane >> 4) * 8 + i;
  int j = n >> 2, g = n & 3;
  int row = g * 512 + j;
  float v = (k < 64) ? w_ih[row * 64 + k] : w_hh[row * 512 + (k - 64)];
  wp[idx] = f2bf(v);
}

// ---- normalize (fused) + conv1d(k=3, VALID) + relu -> seq[t][b][oc] bf16
__global__ __launch_bounds__(256) void k_conv(const float* __restrict__ inX,
                                              const float* __restrict__ conv_w,
                                              const float* __restrict__ conv_b,
                                              u16* __restrict__ seq) {
  __shared__ float xn[6][128];
  __shared__ float rn[6];
  int b = blockIdx.y;
  int t0 = blockIdx.x * 4;
  int tid = threadIdx.x;
  for (int e = tid; e < 768; e += 256) {
    int ri = e >> 7, col = e & 127;
    int t = t0 + ri;
    xn[ri][col] = (t < 1024) ? inX[((size_t)b * 1024 + t) * 128 + col] : 0.f;
  }
  __syncthreads();
  if (tid < 192) {                                 // 6 rows x 32 lanes
    int ri = tid >> 5, l32 = tid & 31;
    float4 v = *reinterpret_cast<const float4*>(&xn[ri][l32 * 4]);
    float s = v.x * v.x + v.y * v.y + v.z * v.z + v.w * v.w;
    #pragma unroll
    for (int d = 1; d < 32; d <<= 1) s += __shfl_xor(s, d, 32);
    if (l32 == 0) rn[ri] = 1.f / fmaxf(sqrtf(s), 1e-12f);
  }
  __syncthreads();
  for (int e = tid; e < 768; e += 256) {
    int ri = e >> 7, col = e & 127;
    xn[ri][col] *= rn[ri];
  }
  __syncthreads();
  int oc = tid & 63, ty = tid >> 6;
  int t = t0 + ty;
  if (t < TP) {
    const float* wr = conv_w + oc * 384;           // (OC, IN, 3) row-major
    float s = conv_b[oc];
    #pragma unroll 4
    for (int i = 0; i < 128; ++i) {
      s += wr[i * 3 + 0] * xn[ty + 0][i]
         + wr[i * 3 + 1] * xn[ty + 1][i]
         + wr[i * 3 + 2] * xn[ty + 2][i];
    }
    s = fmaxf(s, 0.f);
    seq[((size_t)t * 64 + b) * 64 + oc] = f2bf(s);
  }
}

// ---- persistent LSTM on ONE XCD (identical to round 8 EXCEPT: ~100KB LDS pad
// forces EXCLUSIVE CU residency — 160KB/CU means max 1 WG/CU, so the 32 workers
// are guaranteed on 32 distinct CUs instead of packed 2-3 per CU at the
// dispatcher's whim. Barrier-locked steps run at the slowest WG's pace, so any
// CU sharing multiplies every step leg by the sharing factor).
__global__ __launch_bounds__(256, 1) void k_lstm(const u16* __restrict__ seq,
                                                 const u16* __restrict__ wp,
                                                 const float* __restrict__ biasp,
                                                 u16* h0buf, u16* h1buf,
                                                 float* __restrict__ hfin,
                                                 unsigned* bar) {
  const int tid = threadIdx.x;
  __shared__ int s_rank;
  __shared__ struct { u16 stage[64][16]; char xpad[100000]; } sm;  // CU-exclusivity pad

  // ---- XCD self-designation (setup only; agent-scope atomics via MALL)
  if (tid == 0) {
    sm.xpad[0] = 0;                                // touch pad (keep allocation)
    unsigned xcd;
    asm volatile("s_getreg_b32 %0, hwreg(HW_REG_XCC_ID)" : "=s"(xcd));
    xcd &= 7u;
    unsigned r = __hip_atomic_fetch_add(&bar[8 + xcd], 1u, __ATOMIC_RELAXED,
                                        __HIP_MEMORY_SCOPE_AGENT);
    if (r == NWRK - 1) {
      unsigned expected = 0u;
      __hip_atomic_compare_exchange_strong(&bar[16], &expected, xcd + 1u,
                                           __ATOMIC_RELAXED, __ATOMIC_RELAXED,
                                           __HIP_MEMORY_SCOPE_AGENT);
    }
    unsigned d;
    while ((d = __hip_atomic_load(&bar[16], __ATOMIC_RELAXED,
                                  __HIP_MEMORY_SCOPE_AGENT)) == 0u)
      __builtin_amdgcn_s_sleep(8);
    s_rank = (xcd == d - 1u && r < NWRK) ? (int)r : -1;
  }
  __syncthreads();
  const int rank = s_rank;

  if (rank < 0) {
    // ---- clock keeper: dependent-FMA spin until all workers signal done.
    const int lane_ = tid & 63;
    float x = (float)tid + 1.0f;
    unsigned d = 0;
    do {
      #pragma unroll
      for (int i = 0; i < 1024; ++i) x = __builtin_fmaf(x, 1.0000001f, 1.0e-30f);
      asm volatile("" :: "v"(x));                  // keep the chain live (no DCE)
      if (lane_ == 0)
        d = __hip_atomic_fetch_add(&bar[64], 0u, __ATOMIC_RELAXED,
                                   __HIP_MEMORY_SCOPE_AGENT);
      d = __shfl(d, 0);
    } while (d < NWRK);
    return;
  }

  const int wave = tid >> 6, lane = tid & 63;
  const int wgl = rank * 4 + wave;                 // 0..127
  const int mt2 = wgl >> 1;                        // 0..63
  const int nh = wgl & 1;                          // batch half
  const int mtA = 2 * mt2, mtB = mtA + 1;
  const int b0n = nh * 32 + (lane & 15);           // batch (n-tile 0)
  const int hi = lane >> 4;                        // 0..3
  const int koff = hi * 8;
  const int ulA = 8 * (wave >> 1) + hi;            // unit within WG's 16-slice
  const int ulB = ulA + 4;
  const int uA = rank * 16 + ulA;                  // global unit ids
  const int uB = rank * 16 + ulB;
  const float4 biasA = *reinterpret_cast<const float4*>(biasp + mtA * 16 + hi * 4);
  const float4 biasB = *reinterpret_cast<const float4*>(biasp + mtB * 16 + hi * 4);

  // preload both weight slices: 2 x 18 k-tiles x 8 bf16/lane = 144 VGPRs
  short8 wA[18], wB[18];
  {
    const u16* wa = wp + (size_t)mtA * (18 * 512) + lane * 8;
    const u16* wb = wp + (size_t)mtB * (18 * 512) + lane * 8;
    #pragma unroll
    for (int kt = 0; kt < 18; ++kt) {
      wA[kt] = *reinterpret_cast<const short8*>(wa + kt * 512);
      wB[kt] = *reinterpret_cast<const short8*>(wb + kt * 512);
    }
  }

  unsigned* cnt = bar;                             // single sync counter
  float cA0 = 0.f, cA1 = 0.f, cB0 = 0.f, cB1 = 0.f;
  f32x4 accA0, accA1, accB0, accB1;

#define XPART(T) do { \
    const u16* xt_ = seq + (size_t)(T) * 4096; \
    short8 x0a = *reinterpret_cast<const short8*>(xt_ + b0n * 64 + koff); \
    short8 x1a = *reinterpret_cast<const short8*>(xt_ + (b0n + 16) * 64 + koff); \
    short8 x0b = *reinterpret_cast<const short8*>(xt_ + b0n * 64 + 32 + koff); \
    short8 x1b = *reinterpret_cast<const short8*>(xt_ + (b0n + 16) * 64 + 32 + koff); \
    f32x4 z_ = {0.f, 0.f, 0.f, 0.f}; \
    accA0 = __builtin_amdgcn_mfma_f32_16x16x32_bf16(wA[0], x0a, z_, 0, 0, 0); \
    accA1 = __builtin_amdgcn_mfma_f32_16x16x32_bf16(wA[0], x1a, z_, 0, 0, 0); \
    accB0 = __builtin_amdgcn_mfma_f32_16x16x32_bf16(wB[0], x0a, z_, 0, 0, 0); \
    accB1 = __builtin_amdgcn_mfma_f32_16x16x32_bf16(wB[0], x1a, z_, 0, 0, 0); \
    accA0 = __builtin_amdgcn_mfma_f32_16x16x32_bf16(wA[1], x0b, accA0, 0, 0, 0); \
    accA1 = __builtin_amdgcn_mfma_f32_16x16x32_bf16(wA[1], x1b, accA1, 0, 0, 0); \
    accB0 = __builtin_amdgcn_mfma_f32_16x16x32_bf16(wB[1], x0b, accB0, 0, 0, 0); \
    accB1 = __builtin_amdgcn_mfma_f32_16x16x32_bf16(wB[1], x1b, accB1, 0, 0, 0); \
  } while (0)

  XPART(0);                                        // x-part for t=0 (h(-1)=0)

  for (int t = 0; t < TP; ++t) {
    // ---- wait for h(t-1): ONE RMW per WG per poll iteration at the XCD L2
    if (t > 0) {
      if (tid == 0) {
        const unsigned tgt = (unsigned)(NWRK * t);
        for (;;) {
          unsigned v = __hip_atomic_fetch_add(cnt, 0u, __ATOMIC_RELAXED,
                                              __HIP_MEMORY_SCOPE_WORKGROUP);
          if (v >= tgt) break;
          __builtin_amdgcn_s_sleep(1);
        }
      }
      __syncthreads();
    }

    const u16* hc = (t & 1) ? h1buf : h0buf;
    u16* hn = (t & 1) ? h0buf : h1buf;

    // ---- issue all 32 h-fragment loads (sc0, from XCD L2), then wait once
    f32x4 hb0[16], hb1[16];
    #pragma unroll
    for (int kt = 0; kt < 16; ++kt) {
      const u16* p0 = hc + b0n * 512 + kt * 32 + koff;
      hb0[kt] = load16_sc0(p0);
      hb1[kt] = load16_sc0(p0 + 16 * 512);
    }
    asm volatile("s_waitcnt vmcnt(0)" ::: "memory");
    __builtin_amdgcn_sched_barrier(0);

    // ---- recurrent MFMAs: 16 kt x 4 (B-fragments shared across mtA/mtB)
    #pragma unroll
    for (int kt = 0; kt < 16; ++kt) {
      short8 b0 = __builtin_bit_cast(short8, hb0[kt]);
      short8 b1 = __builtin_bit_cast(short8, hb1[kt]);
      accA0 = __builtin_amdgcn_mfma_f32_16x16x32_bf16(wA[kt + 2], b0, accA0, 0, 0, 0);
      accA1 = __builtin_amdgcn_mfma_f32_16x16x32_bf16(wA[kt + 2], b1, accA1, 0, 0, 0);
      accB0 = __builtin_amdgcn_mfma_f32_16x16x32_bf16(wB[kt + 2], b0, accB0, 0, 0, 0);
      accB1 = __builtin_amdgcn_mfma_f32_16x16x32_bf16(wB[kt + 2], b1, accB1, 0, 0, 0);
    }

    // ---- gates (i,f,g,o in acc[0..3] of each lane, per mt x batch-tile)
    float iA0 = sigmoidf_(accA0[0] + biasA.x);
    float fA0 = sigmoidf_(accA0[1] + biasA.y);
    float gA0 = tanhf_(accA0[2] + biasA.z);
    float oA0 = sigmoidf_(accA0[3] + biasA.w);
    cA0 = fA0 * cA0 + iA0 * gA0;
    float hvA0 = oA0 * tanhf_(cA0);
    float iA1 = sigmoidf_(accA1[0] + biasA.x);
    float fA1 = sigmoidf_(accA1[1] + biasA.y);
    float gA1 = tanhf_(accA1[2] + biasA.z);
    float oA1 = sigmoidf_(accA1[3] + biasA.w);
    cA1 = fA1 * cA1 + iA1 * gA1;
    float hvA1 = oA1 * tanhf_(cA1);
    float iB0 = sigmoidf_(accB0[0] + biasB.x);
    float fB0 = sigmoidf_(accB0[1] + biasB.y);
    float gB0 = tanhf_(accB0[2] + biasB.z);
    float oB0 = sigmoidf_(accB0[3] + biasB.w);
    cB0 = fB0 * cB0 + iB0 * gB0;
    float hvB0 = oB0 * tanhf_(cB0);
    float iB1 = sigmoidf_(accB1[0] + biasB.x);
    float fB1 = sigmoidf_(accB1[1] + biasB.y);
    float gB1 = tanhf_(accB1[2] + biasB.z);
    float oB1 = sigmoidf_(accB1[3] + biasB.w);
    cB1 = fB1 * cB1 + iB1 * gB1;
    float hvB1 = oB1 * tanhf_(cB1);

    // ---- stage h in LDS (WG owns units [16*rank, 16*rank+16))
    sm.stage[b0n][ulA] = f2bf(hvA0);
    sm.stage[b0n + 16][ulA] = f2bf(hvA1);
    sm.stage[b0n][ulB] = f2bf(hvB0);
    sm.stage[b0n + 16][ulB] = f2bf(hvB1);
    if (t == TP - 1) {
      hfin[b0n * 512 + uA] = hvA0;
      hfin[(b0n + 16) * 512 + uA] = hvA1;
      hfin[b0n * 512 + uB] = hvB0;
      hfin[(b0n + 16) * 512 + uB] = hvB1;
    }
    __syncthreads();

    // ---- coalesced sc0 h stores: 128 threads x 16B into XCD L2
    if (tid < 128) {
      int b = tid >> 1, ch = tid & 1;
      f32x4 val = *reinterpret_cast<const f32x4*>(&sm.stage[b][ch * 8]);
      store16_sc0(hn + b * 512 + rank * 16 + ch * 8, val);
    }
    asm volatile("s_waitcnt vmcnt(0)" ::: "memory");
    __syncthreads();                               // all waves' stores drained

    // ---- signal: ONE atomic RMW per WG (L2 execution point = visibility)
    if (tid == 0)
      __hip_atomic_fetch_add(cnt, 1u, __ATOMIC_RELAXED, __HIP_MEMORY_SCOPE_WORKGROUP);

    // ---- x-part prefetch for t+1 (plain cached loads) overlaps others' polls
    if (t + 1 < TP) XPART(t + 1);
  }
#undef XPART

  // ---- tell the clock keepers we're done (MALL-scope RMW, cross-XCD visible)
  if (tid == 0)
    __hip_atomic_fetch_add(&bar[64], 1u, __ATOMIC_RELAXED, __HIP_MEMORY_SCOPE_AGENT);
}

// ---- final linear: out[b][o] = h . lin_w[o] + lin_b[o]  (fp32)
__global__ void k_fc(const float* __restrict__ hfin, const float* __restrict__ lin_w,
                     const float* __restrict__ lin_b, float* __restrict__ out) {
  int b = blockIdx.x, o = threadIdx.x;             // 128 threads
  const float* hp = hfin + b * 512;
  const float* wq = lin_w + o * 512;
  float s = lin_b[o];
  #pragma unroll 4
  for (int j = 0; j < 512; ++j) s += hp[j] * wq[j];
  out[b * 128 + o] = s;
}

extern "C" void kernel_launch(void* const* d_in, const int* in_sizes, int n_in,
                              void* d_out, int out_size, void* d_ws, size_t ws_size,
                              hipStream_t stream) {
  const float* inX    = (const float*)d_in[0];
  const float* conv_w = (const float*)d_in[2];
  const float* conv_b = (const float*)d_in[3];
  const float* w_ih   = (const float*)d_in[4];
  const float* w_hh   = (const float*)d_in[5];
  const float* b_ih   = (const float*)d_in[6];
  const float* b_hh   = (const float*)d_in[7];
  const float* lin_w  = (const float*)d_in[8];
  const float* lin_b  = (const float*)d_in[9];
  float* out = (float*)d_out;
  char* ws = (char*)d_ws;
  u16*      wpack = (u16*)(ws + OFF_WPACK);
  u16*      seq   = (u16*)(ws + OFF_SEQ);
  float*    biasp = (float*)(ws + OFF_BIAS);
  u16*      h0b   = (u16*)(ws + OFF_H0);
  u16*      h1b   = (u16*)(ws + OFF_H1);
  float*    hfin  = (float*)(ws + OFF_HFIN);
  unsigned* bar   = (unsigned*)(ws + OFF_BAR);

  k_init<<<dim3(128), dim3(256), 0, stream>>>(b_ih, b_hh, biasp, (unsigned*)(ws + OFF_H0), bar);
  k_pack<<<dim3(4608), dim3(256), 0, stream>>>(w_ih, w_hh, wpack);
  k_conv<<<dim3(256, 64), dim3(256), 0, stream>>>(inX, conv_w, conv_b, seq);
  k_lstm<<<dim3(256), dim3(256), 0, stream>>>(seq, wpack, biasp, h0b, h1b, hfin, bar);
  k_fc<<<dim3(64), dim3(128), 0, stream>>>(hfin, lin_w, lin_b, out);
}

// Round 12
// 4340.341 us; speedup vs baseline: 2.2158x; 1.5323x over previous
//
#include <hip/hip_runtime.h>

typedef __attribute__((ext_vector_type(8))) short short8;
typedef __attribute__((ext_vector_type(4))) float f32x4;
typedef unsigned short u16;
typedef unsigned long long u64;

#define TP   1022      // conv output length = T-2
#define NWRK 32        // worker WGs (all on one XCD)

// ws layout (byte offsets, all 256-aligned)
#define OFF_WPACK   0            // 2048*576*2   = 2359296
#define OFF_SEQ     2359296      // 1022*64*64*2 = 8372224
#define OFF_BIAS    10993664     // 2048*4       = 8192
#define OFF_H0      11001856     // 64*512*2     = 65536
#define OFF_H1      11067392     // 64*512*2     = 65536
#define OFF_HFIN    11132928     // 64*512*4     = 131072
#define OFF_BAR     11264000     // cnt @0, xcdcnt @+32B, designated @+64B, done @+256B

__device__ inline u16 f2bf(float x) {
  union { float f; unsigned u; } un; un.f = x;
  unsigned r = un.u + 0x7fffu + ((un.u >> 16) & 1u);  // RNE
  return (u16)(r >> 16);
}
__device__ inline float sigmoidf_(float x) { return 1.f / (1.f + __expf(-x)); }
__device__ inline float tanhf_(float x)    { return 2.f / (1.f + __expf(-2.f * x)) - 1.f; }

// 16B load/store served by the XCD-local L2 (sc0 bypasses L1 — required because
// h lines are re-read every 2 steps and would otherwise hit stale L1 data).
__device__ inline f32x4 load16_sc0(const void* p) {
  f32x4 r;
  asm volatile("global_load_dwordx4 %0, %1, off sc0" : "=v"(r) : "v"(p) : "memory");
  return r;
}
__device__ inline void store16_sc0(void* p, f32x4 v) {
  asm volatile("global_store_dwordx4 %0, %1, off sc0" :: "v"(p), "v"(v) : "memory");
}

// ---- init: zero h buffers + barrier region, build packed bias (b_ih+b_hh, n=4j+g)
__global__ void k_init(const float* __restrict__ b_ih, const float* __restrict__ b_hh,
                       float* __restrict__ biasp, unsigned* __restrict__ hzero,
                       unsigned* __restrict__ bar) {
  int tid = blockIdx.x * 256 + threadIdx.x;
  if (tid < 32768) hzero[tid] = 0u;                 // both h bufs (131072 B)
  if (tid < 2048) {
    int j = tid >> 2, g = tid & 3;
    int row = g * 512 + j;
    biasp[tid] = b_ih[row] + b_hh[row];
  }
  if (tid < 128) bar[tid] = 0u;                     // cnt + xcdcnt + designated + done
}

// ---- pack W = [w_ih ; w_hh] (2048 x 576) into MFMA A-fragment order, bf16.
__global__ void k_pack(const float* __restrict__ w_ih, const float* __restrict__ w_hh,
                       u16* __restrict__ wp) {
  int idx = blockIdx.x * 256 + threadIdx.x;        // < 128*18*512 = 1179648
  int nt = idx / 9216;
  int rem = idx - nt * 9216;
  int kt = rem / 512;
  int rem2 = rem - kt * 512;
  int lane = rem2 >> 3, i = rem2 & 7;
  int n = nt * 16 + (lane & 15);
  int k = kt * 32 + (lane >> 4) * 8 + i;
  int j = n >> 2, g = n & 3;
  int row = g * 512 + j;
  float v = (k < 64) ? w_ih[row * 64 + k] : w_hh[row * 512 + (k - 64)];
  wp[idx] = f2bf(v);
}

// ---- normalize (fused) + conv1d(k=3, VALID) + relu -> seq[t][b][oc] bf16
__global__ __launch_bounds__(256) void k_conv(const float* __restrict__ inX,
                                              const float* __restrict__ conv_w,
                                              const float* __restrict__ conv_b,
                                              u16* __restrict__ seq) {
  __shared__ float xn[6][128];
  __shared__ float rn[6];
  int b = blockIdx.y;
  int t0 = blockIdx.x * 4;
  int tid = threadIdx.x;
  for (int e = tid; e < 768; e += 256) {
    int ri = e >> 7, col = e & 127;
    int t = t0 + ri;
    xn[ri][col] = (t < 1024) ? inX[((size_t)b * 1024 + t) * 128 + col] : 0.f;
  }
  __syncthreads();
  if (tid < 192) {                                 // 6 rows x 32 lanes
    int ri = tid >> 5, l32 = tid & 31;
    float4 v = *reinterpret_cast<const float4*>(&xn[ri][l32 * 4]);
    float s = v.x * v.x + v.y * v.y + v.z * v.z + v.w * v.w;
    #pragma unroll
    for (int d = 1; d < 32; d <<= 1) s += __shfl_xor(s, d, 32);
    if (l32 == 0) rn[ri] = 1.f / fmaxf(sqrtf(s), 1e-12f);
  }
  __syncthreads();
  for (int e = tid; e < 768; e += 256) {
    int ri = e >> 7, col = e & 127;
    xn[ri][col] *= rn[ri];
  }
  __syncthreads();
  int oc = tid & 63, ty = tid >> 6;
  int t = t0 + ty;
  if (t < TP) {
    const float* wr = conv_w + oc * 384;           // (OC, IN, 3) row-major
    float s = conv_b[oc];
    #pragma unroll 4
    for (int i = 0; i < 128; ++i) {
      s += wr[i * 3 + 0] * xn[ty + 0][i]
         + wr[i * 3 + 1] * xn[ty + 1][i]
         + wr[i * 3 + 2] * xn[ty + 2][i];
    }
    s = fmaxf(s, 0.f);
    seq[((size_t)t * 64 + b) * 64 + oc] = f2bf(s);
  }
}

// ---- persistent LSTM on ONE XCD. Sync/store/prefetch byte-identical to the
// passing round-8 kernel. ONE change: h(t-1) is staged into LDS with COALESCED
// sc0 loads (wave = one 1KB row per pass), XOR-swizzled; MFMA B-fragments read
// from LDS. This cuts the per-step L2 request count 16x (262144 scattered
// 16B-line requests -> 16384 coalesced 128B requests) — the invariant ~6us/step
// matched the scatter-serialization arithmetic, and it is the one element never
// varied across rounds 5-10.
__global__ __launch_bounds__(256, 1) void k_lstm(const u16* __restrict__ seq,
                                                 const u16* __restrict__ wp,
                                                 const float* __restrict__ biasp,
                                                 u16* h0buf, u16* h1buf,
                                                 float* __restrict__ hfin,
                                                 unsigned* bar) {
  const int tid = threadIdx.x;
  __shared__ int s_rank;
  __shared__ __align__(16) char hl[65536];         // staged h(t-1), XOR-swizzled
  __shared__ u16 stage[64][16];                    // [batch][unit-slice] out-stage

  // ---- XCD self-designation (setup only; agent-scope atomics via MALL)
  if (tid == 0) {
    unsigned xcd;
    asm volatile("s_getreg_b32 %0, hwreg(HW_REG_XCC_ID)" : "=s"(xcd));
    xcd &= 7u;
    unsigned r = __hip_atomic_fetch_add(&bar[8 + xcd], 1u, __ATOMIC_RELAXED,
                                        __HIP_MEMORY_SCOPE_AGENT);
    if (r == NWRK - 1) {
      unsigned expected = 0u;
      __hip_atomic_compare_exchange_strong(&bar[16], &expected, xcd + 1u,
                                           __ATOMIC_RELAXED, __ATOMIC_RELAXED,
                                           __HIP_MEMORY_SCOPE_AGENT);
    }
    unsigned d;
    while ((d = __hip_atomic_load(&bar[16], __ATOMIC_RELAXED,
                                  __HIP_MEMORY_SCOPE_AGENT)) == 0u)
      __builtin_amdgcn_s_sleep(8);
    s_rank = (xcd == d - 1u && r < NWRK) ? (int)r : -1;
  }
  __syncthreads();
  const int rank = s_rank;

  if (rank < 0) {
    // ---- clock keeper: dependent-FMA spin until all workers signal done.
    const int lane_ = tid & 63;
    float x = (float)tid + 1.0f;
    unsigned d = 0;
    do {
      #pragma unroll
      for (int i = 0; i < 1024; ++i) x = __builtin_fmaf(x, 1.0000001f, 1.0e-30f);
      asm volatile("" :: "v"(x));                  // keep the chain live (no DCE)
      if (lane_ == 0)
        d = __hip_atomic_fetch_add(&bar[64], 0u, __ATOMIC_RELAXED,
                                   __HIP_MEMORY_SCOPE_AGENT);
      d = __shfl(d, 0);
    } while (d < NWRK);
    return;
  }

  const int wave = tid >> 6, lane = tid & 63;
  const int wgl = rank * 4 + wave;                 // 0..127
  const int mt2 = wgl >> 1;                        // 0..63
  const int nh = wgl & 1;                          // batch half
  const int mtA = 2 * mt2, mtB = mtA + 1;
  const int b0n = nh * 32 + (lane & 15);           // batch (n-tile 0)
  const int hi = lane >> 4;                        // 0..3
  const int koff = hi * 8;
  const int ulA = 8 * (wave >> 1) + hi;            // unit within WG's 16-slice
  const int ulB = ulA + 4;
  const int uA = rank * 16 + ulA;                  // global unit ids
  const int uB = rank * 16 + ulB;
  const float4 biasA = *reinterpret_cast<const float4*>(biasp + mtA * 16 + hi * 4);
  const float4 biasB = *reinterpret_cast<const float4*>(biasp + mtB * 16 + hi * 4);

  // preload both weight slices: 2 x 18 k-tiles x 8 bf16/lane = 144 VGPRs
  short8 wA[18], wB[18];
  {
    const u16* wa = wp + (size_t)mtA * (18 * 512) + lane * 8;
    const u16* wb = wp + (size_t)mtB * (18 * 512) + lane * 8;
    #pragma unroll
    for (int kt = 0; kt < 18; ++kt) {
      wA[kt] = *reinterpret_cast<const short8*>(wa + kt * 512);
      wB[kt] = *reinterpret_cast<const short8*>(wb + kt * 512);
    }
  }

  unsigned* cnt = bar;                             // single sync counter
  float cA0 = 0.f, cA1 = 0.f, cB0 = 0.f, cB1 = 0.f;
  f32x4 accA0, accA1, accB0, accB1;

  // LDS fragment-read constants (row = global batch; bank swizzle by row&7)
  const int r0base = b0n * 1024;
  const int r1base = (b0n + 16) * 1024;
  const int rmask  = (b0n & 7) << 4;               // (b0n+16)&7 == b0n&7
  const int fr_hib = hi * 16;

#define XPART(T) do { \
    const u16* xt_ = seq + (size_t)(T) * 4096; \
    short8 x0a = *reinterpret_cast<const short8*>(xt_ + b0n * 64 + koff); \
    short8 x1a = *reinterpret_cast<const short8*>(xt_ + (b0n + 16) * 64 + koff); \
    short8 x0b = *reinterpret_cast<const short8*>(xt_ + b0n * 64 + 32 + koff); \
    short8 x1b = *reinterpret_cast<const short8*>(xt_ + (b0n + 16) * 64 + 32 + koff); \
    f32x4 z_ = {0.f, 0.f, 0.f, 0.f}; \
    accA0 = __builtin_amdgcn_mfma_f32_16x16x32_bf16(wA[0], x0a, z_, 0, 0, 0); \
    accA1 = __builtin_amdgcn_mfma_f32_16x16x32_bf16(wA[0], x1a, z_, 0, 0, 0); \
    accB0 = __builtin_amdgcn_mfma_f32_16x16x32_bf16(wB[0], x0a, z_, 0, 0, 0); \
    accB1 = __builtin_amdgcn_mfma_f32_16x16x32_bf16(wB[0], x1a, z_, 0, 0, 0); \
    accA0 = __builtin_amdgcn_mfma_f32_16x16x32_bf16(wA[1], x0b, accA0, 0, 0, 0); \
    accA1 = __builtin_amdgcn_mfma_f32_16x16x32_bf16(wA[1], x1b, accA1, 0, 0, 0); \
    accB0 = __builtin_amdgcn_mfma_f32_16x16x32_bf16(wB[1], x0b, accB0, 0, 0, 0); \
    accB1 = __builtin_amdgcn_mfma_f32_16x16x32_bf16(wB[1], x1b, accB1, 0, 0, 0); \
  } while (0)

  XPART(0);                                        // x-part for t=0 (h(-1)=0)

  for (int t = 0; t < TP; ++t) {
    // ---- wait for h(t-1): ONE RMW per WG per poll iteration at the XCD L2
    if (t > 0) {
      if (tid == 0) {
        const unsigned tgt = (unsigned)(NWRK * t);
        for (;;) {
          unsigned v = __hip_atomic_fetch_add(cnt, 0u, __ATOMIC_RELAXED,
                                              __HIP_MEMORY_SCOPE_WORKGROUP);
          if (v >= tgt) break;
          __builtin_amdgcn_s_sleep(1);
        }
      }
      __syncthreads();
    }

    const u16* hc = (t & 1) ? h1buf : h0buf;
    u16* hn = (t & 1) ? h0buf : h1buf;

    // ---- stage FULL 64KB h(t-1) into swizzled LDS: coalesced sc0 loads.
    // chunk = pass*256 + tid (16B each); a wave covers exactly one 1KB row per
    // pass -> 128B-line-granular L2 traffic. LDS write: off ^ ((row&7)<<4).
    {
      f32x4 va[8], vb[8];
      #pragma unroll
      for (int p = 0; p < 8; ++p)
        va[p] = load16_sc0(hc + (size_t)(p * 256 + tid) * 8);
      #pragma unroll
      for (int p = 0; p < 8; ++p)
        vb[p] = load16_sc0(hc + (size_t)((p + 8) * 256 + tid) * 8);
      asm volatile("s_waitcnt vmcnt(8)" ::: "memory");
      __builtin_amdgcn_sched_barrier(0);
      #pragma unroll
      for (int p = 0; p < 8; ++p) {
        int chunk = p * 256 + tid;
        int row = chunk >> 6, off = (chunk & 63) * 16;
        *reinterpret_cast<f32x4*>(hl + row * 1024 + (off ^ ((row & 7) << 4))) = va[p];
      }
      asm volatile("s_waitcnt vmcnt(0)" ::: "memory");
      __builtin_amdgcn_sched_barrier(0);
      #pragma unroll
      for (int p = 0; p < 8; ++p) {
        int chunk = (p + 8) * 256 + tid;
        int row = chunk >> 6, off = (chunk & 63) * 16;
        *reinterpret_cast<f32x4*>(hl + row * 1024 + (off ^ ((row & 7) << 4))) = vb[p];
      }
    }
    __syncthreads();

    // ---- recurrent MFMAs: B-fragments from swizzled LDS (even bank spread)
    #pragma unroll
    for (int kt = 0; kt < 16; ++kt) {
      int off = (kt * 64 + fr_hib) ^ rmask;
      short8 b0 = *reinterpret_cast<const short8*>(hl + r0base + off);
      short8 b1 = *reinterpret_cast<const short8*>(hl + r1base + off);
      accA0 = __builtin_amdgcn_mfma_f32_16x16x32_bf16(wA[kt + 2], b0, accA0, 0, 0, 0);
      accA1 = __builtin_amdgcn_mfma_f32_16x16x32_bf16(wA[kt + 2], b1, accA1, 0, 0, 0);
      accB0 = __builtin_amdgcn_mfma_f32_16x16x32_bf16(wB[kt + 2], b0, accB0, 0, 0, 0);
      accB1 = __builtin_amdgcn_mfma_f32_16x16x32_bf16(wB[kt + 2], b1, accB1, 0, 0, 0);
    }

    // ---- gates (i,f,g,o in acc[0..3] of each lane, per mt x batch-tile)
    float iA0 = sigmoidf_(accA0[0] + biasA.x);
    float fA0 = sigmoidf_(accA0[1] + biasA.y);
    float gA0 = tanhf_(accA0[2] + biasA.z);
    float oA0 = sigmoidf_(accA0[3] + biasA.w);
    cA0 = fA0 * cA0 + iA0 * gA0;
    float hvA0 = oA0 * tanhf_(cA0);
    float iA1 = sigmoidf_(accA1[0] + biasA.x);
    float fA1 = sigmoidf_(accA1[1] + biasA.y);
    float gA1 = tanhf_(accA1[2] + biasA.z);
    float oA1 = sigmoidf_(accA1[3] + biasA.w);
    cA1 = fA1 * cA1 + iA1 * gA1;
    float hvA1 = oA1 * tanhf_(cA1);
    float iB0 = sigmoidf_(accB0[0] + biasB.x);
    float fB0 = sigmoidf_(accB0[1] + biasB.y);
    float gB0 = tanhf_(accB0[2] + biasB.z);
    float oB0 = sigmoidf_(accB0[3] + biasB.w);
    cB0 = fB0 * cB0 + iB0 * gB0;
    float hvB0 = oB0 * tanhf_(cB0);
    float iB1 = sigmoidf_(accB1[0] + biasB.x);
    float fB1 = sigmoidf_(accB1[1] + biasB.y);
    float gB1 = tanhf_(accB1[2] + biasB.z);
    float oB1 = sigmoidf_(accB1[3] + biasB.w);
    cB1 = fB1 * cB1 + iB1 * gB1;
    float hvB1 = oB1 * tanhf_(cB1);

    // ---- stage h in LDS (WG owns units [16*rank, 16*rank+16))
    stage[b0n][ulA] = f2bf(hvA0);
    stage[b0n + 16][ulA] = f2bf(hvA1);
    stage[b0n][ulB] = f2bf(hvB0);
    stage[b0n + 16][ulB] = f2bf(hvB1);
    if (t == TP - 1) {
      hfin[b0n * 512 + uA] = hvA0;
      hfin[(b0n + 16) * 512 + uA] = hvA1;
      hfin[b0n * 512 + uB] = hvB0;
      hfin[(b0n + 16) * 512 + uB] = hvB1;
    }
    __syncthreads();

    // ---- coalesced sc0 h stores: 128 threads x 16B into XCD L2
    if (tid < 128) {
      int b = tid >> 1, ch = tid & 1;
      f32x4 val = *reinterpret_cast<const f32x4*>(&stage[b][ch * 8]);
      store16_sc0(hn + b * 512 + rank * 16 + ch * 8, val);
    }
    asm volatile("s_waitcnt vmcnt(0)" ::: "memory");
    __syncthreads();                               // all waves' stores drained

    // ---- signal: ONE atomic RMW per WG (L2 execution point = visibility)
    if (tid == 0)
      __hip_atomic_fetch_add(cnt, 1u, __ATOMIC_RELAXED, __HIP_MEMORY_SCOPE_WORKGROUP);

    // ---- x-part prefetch for t+1 (plain cached loads) overlaps others' polls
    if (t + 1 < TP) XPART(t + 1);
  }
#undef XPART

  // ---- tell the clock keepers we're done (MALL-scope RMW, cross-XCD visible)
  if (tid == 0)
    __hip_atomic_fetch_add(&bar[64], 1u, __ATOMIC_RELAXED, __HIP_MEMORY_SCOPE_AGENT);
}

// ---- final linear: out[b][o] = h . lin_w[o] + lin_b[o]  (fp32)
__global__ void k_fc(const float* __restrict__ hfin, const float* __restrict__ lin_w,
                     const float* __restrict__ lin_b, float* __restrict__ out) {
  int b = blockIdx.x, o = threadIdx.x;             // 128 threads
  const float* hp = hfin + b * 512;
  const float* wq = lin_w + o * 512;
  float s = lin_b[o];
  #pragma unroll 4
  for (int j = 0; j < 512; ++j) s += hp[j] * wq[j];
  out[b * 128 + o] = s;
}

extern "C" void kernel_launch(void* const* d_in, const int* in_sizes, int n_in,
                              void* d_out, int out_size, void* d_ws, size_t ws_size,
                              hipStream_t stream) {
  const float* inX    = (const float*)d_in[0];
  const float* conv_w = (const float*)d_in[2];
  const float* conv_b = (const float*)d_in[3];
  const float* w_ih   = (const float*)d_in[4];
  const float* w_hh   = (const float*)d_in[5];
  const float* b_ih   = (const float*)d_in[6];
  const float* b_hh   = (const float*)d_in[7];
  const float* lin_w  = (const float*)d_in[8];
  const float* lin_b  = (const float*)d_in[9];
  float* out = (float*)d_out;
  char* ws = (char*)d_ws;
  u16*      wpack = (u16*)(ws + OFF_WPACK);
  u16*      seq   = (u16*)(ws + OFF_SEQ);
  float*    biasp = (float*)(ws + OFF_BIAS);
  u16*      h0b   = (u16*)(ws + OFF_H0);
  u16*      h1b   = (u16*)(ws + OFF_H1);
  float*    hfin  = (float*)(ws + OFF_HFIN);
  unsigned* bar   = (unsigned*)(ws + OFF_BAR);

  k_init<<<dim3(128), dim3(256), 0, stream>>>(b_ih, b_hh, biasp, (unsigned*)(ws + OFF_H0), bar);
  k_pack<<<dim3(4608), dim3(256), 0, stream>>>(w_ih, w_hh, wpack);
  k_conv<<<dim3(256, 64), dim3(256), 0, stream>>>(inX, conv_w, conv_b, seq);
  k_lstm<<<dim3(256), dim3(256), 0, stream>>>(seq, wpack, biasp, h0b, h1b, hfin, bar);
  k_fc<<<dim3(64), dim3(128), 0, stream>>>(hfin, lin_w, lin_b, out);
}

// Round 13
// 3936.960 us; speedup vs baseline: 2.4429x; 1.1025x over previous
//
#include <hip/hip_runtime.h>

typedef __attribute__((ext_vector_type(8))) short short8;
typedef __attribute__((ext_vector_type(4))) float f32x4;
typedef unsigned short u16;
typedef unsigned long long u64;

#define TP   1022      // conv output length = T-2
#define NWRK 32        // worker WGs (one XCD): 2 batch-groups x 16

// ws layout (byte offsets, all 256-aligned)
#define OFF_WPACK   0            // 2048*576*2   = 2359296
#define OFF_SEQ     2359296      // 1022*64*64*2 = 8372224
#define OFF_BIAS    10993664     // 2048*4       = 8192
#define OFF_H0      11001856     // 64*512*2     = 65536
#define OFF_H1      11067392     // 64*512*2     = 65536
#define OFF_HFIN    11132928     // 64*512*4     = 131072
#define OFF_BAR     11264000     // cnt @0, xcdcnt @+32B, designated @+64B, done @+256B

__device__ inline u16 f2bf(float x) {
  union { float f; unsigned u; } un; un.f = x;
  unsigned r = un.u + 0x7fffu + ((un.u >> 16) & 1u);  // RNE
  return (u16)(r >> 16);
}
__device__ inline float sigmoidf_(float x) { return 1.f / (1.f + __expf(-x)); }
__device__ inline float tanhf_(float x)    { return 2.f / (1.f + __expf(-2.f * x)) - 1.f; }

// 16B load/store served by the XCD-local L2 (sc0 bypasses L1 — required because
// h lines are re-read every 2 steps and would otherwise hit stale L1 data).
__device__ inline f32x4 load16_sc0(const void* p) {
  f32x4 r;
  asm volatile("global_load_dwordx4 %0, %1, off sc0" : "=v"(r) : "v"(p) : "memory");
  return r;
}
__device__ inline void store16_sc0(void* p, f32x4 v) {
  asm volatile("global_store_dwordx4 %0, %1, off sc0" :: "v"(p), "v"(v) : "memory");
}

// ---- init: zero h buffers + barrier region, build packed bias (b_ih+b_hh, n=4j+g)
__global__ void k_init(const float* __restrict__ b_ih, const float* __restrict__ b_hh,
                       float* __restrict__ biasp, unsigned* __restrict__ hzero,
                       unsigned* __restrict__ bar) {
  int tid = blockIdx.x * 256 + threadIdx.x;
  if (tid < 32768) hzero[tid] = 0u;                 // both h bufs (131072 B)
  if (tid < 2048) {
    int j = tid >> 2, g = tid & 3;
    int row = g * 512 + j;
    biasp[tid] = b_ih[row] + b_hh[row];
  }
  if (tid < 128) bar[tid] = 0u;                     // cnt + xcdcnt + designated + done
}

// ---- pack W = [w_ih ; w_hh] (2048 x 576) into MFMA A-fragment order, bf16.
__global__ void k_pack(const float* __restrict__ w_ih, const float* __restrict__ w_hh,
                       u16* __restrict__ wp) {
  int idx = blockIdx.x * 256 + threadIdx.x;        // < 128*18*512 = 1179648
  int nt = idx / 9216;
  int rem = idx - nt * 9216;
  int kt = rem / 512;
  int rem2 = rem - kt * 512;
  int lane = rem2 >> 3, i = rem2 & 7;
  int n = nt * 16 + (lane & 15);
  int k = kt * 32 + (lane >> 4) * 8 + i;
  int j = n >> 2, g = n & 3;
  int row = g * 512 + j;
  float v = (k < 64) ? w_ih[row * 64 + k] : w_hh[row * 512 + (k - 64)];
  wp[idx] = f2bf(v);
}

// ---- normalize (fused) + conv1d(k=3, VALID) + relu -> seq[t][b][oc] bf16
__global__ __launch_bounds__(256) void k_conv(const float* __restrict__ inX,
                                              const float* __restrict__ conv_w,
                                              const float* __restrict__ conv_b,
                                              u16* __restrict__ seq) {
  __shared__ float xn[6][128];
  __shared__ float rn[6];
  int b = blockIdx.y;
  int t0 = blockIdx.x * 4;
  int tid = threadIdx.x;
  for (int e = tid; e < 768; e += 256) {
    int ri = e >> 7, col = e & 127;
    int t = t0 + ri;
    xn[ri][col] = (t < 1024) ? inX[((size_t)b * 1024 + t) * 128 + col] : 0.f;
  }
  __syncthreads();
  if (tid < 192) {                                 // 6 rows x 32 lanes
    int ri = tid >> 5, l32 = tid & 31;
    float4 v = *reinterpret_cast<const float4*>(&xn[ri][l32 * 4]);
    float s = v.x * v.x + v.y * v.y + v.z * v.z + v.w * v.w;
    #pragma unroll
    for (int d = 1; d < 32; d <<= 1) s += __shfl_xor(s, d, 32);
    if (l32 == 0) rn[ri] = 1.f / fmaxf(sqrtf(s), 1e-12f);
  }
  __syncthreads();
  for (int e = tid; e < 768; e += 256) {
    int ri = e >> 7, col = e & 127;
    xn[ri][col] *= rn[ri];
  }
  __syncthreads();
  int oc = tid & 63, ty = tid >> 6;
  int t = t0 + ty;
  if (t < TP) {
    const float* wr = conv_w + oc * 384;           // (OC, IN, 3) row-major
    float s = conv_b[oc];
    #pragma unroll 4
    for (int i = 0; i < 128; ++i) {
      s += wr[i * 3 + 0] * xn[ty + 0][i]
         + wr[i * 3 + 1] * xn[ty + 1][i]
         + wr[i * 3 + 2] * xn[ty + 2][i];
    }
    s = fmaxf(s, 0.f);
    seq[((size_t)t * 64 + b) * 64 + oc] = f2bf(s);
  }
}

// ---- persistent LSTM on ONE XCD. Sync wiring BYTE-IDENTICAL to the passing
// round-12 kernel (single counter @bar[0], done @bar[64]; both groups share the
// counter and lockstep). Change: batch-split into 2 groups of 16 WGs — group g
// computes ALL 512 units for batches 32g..32g+31, so each WG stages only its
// group's 32KB h-half (halves L2 line-serves and LDS write traffic). Out-stage
// padded to [32][40] (80B rows) to kill the 16-way u16-write bank conflict.
__global__ __launch_bounds__(256, 1) void k_lstm(const u16* __restrict__ seq,
                                                 const u16* __restrict__ wp,
                                                 const float* __restrict__ biasp,
                                                 u16* h0buf, u16* h1buf,
                                                 float* __restrict__ hfin,
                                                 unsigned* bar) {
  const int tid = threadIdx.x;
  __shared__ int s_rank;
  __shared__ __align__(16) char hl[32768];         // staged group h-half, swizzled
  __shared__ u16 ostage[32][40];                   // [batch_local][unit_local], padded

  // ---- XCD self-designation (setup only; agent-scope atomics via MALL)
  if (tid == 0) {
    unsigned xcd;
    asm volatile("s_getreg_b32 %0, hwreg(HW_REG_XCC_ID)" : "=s"(xcd));
    xcd &= 7u;
    unsigned r = __hip_atomic_fetch_add(&bar[8 + xcd], 1u, __ATOMIC_RELAXED,
                                        __HIP_MEMORY_SCOPE_AGENT);
    if (r == NWRK - 1) {
      unsigned expected = 0u;
      __hip_atomic_compare_exchange_strong(&bar[16], &expected, xcd + 1u,
                                           __ATOMIC_RELAXED, __ATOMIC_RELAXED,
                                           __HIP_MEMORY_SCOPE_AGENT);
    }
    unsigned d;
    while ((d = __hip_atomic_load(&bar[16], __ATOMIC_RELAXED,
                                  __HIP_MEMORY_SCOPE_AGENT)) == 0u)
      __builtin_amdgcn_s_sleep(8);
    s_rank = (xcd == d - 1u && r < NWRK) ? (int)r : -1;
  }
  __syncthreads();
  const int rank = s_rank;

  if (rank < 0) {
    // ---- clock keeper: dependent-FMA spin until all workers signal done.
    const int lane_ = tid & 63;
    float x = (float)tid + 1.0f;
    unsigned d = 0;
    do {
      #pragma unroll
      for (int i = 0; i < 1024; ++i) x = __builtin_fmaf(x, 1.0000001f, 1.0e-30f);
      asm volatile("" :: "v"(x));                  // keep the chain live (no DCE)
      if (lane_ == 0)
        d = __hip_atomic_fetch_add(&bar[64], 0u, __ATOMIC_RELAXED,
                                   __HIP_MEMORY_SCOPE_AGENT);
      d = __shfl(d, 0);
    } while (d < NWRK);
    return;
  }

  const int wave = tid >> 6, lane = tid & 63;
  const int g   = rank >> 4;                       // batch group 0/1
  const int wgi = rank & 15;                       // index within group
  const int B0  = g * 32;                          // group's batch base
  const int U0  = wgi * 32;                        // WG's unit base
  const int mt2 = wgi * 4 + wave;                  // 0..63 within group
  const int mtA = 2 * mt2, mtB = mtA + 1;          // unit m-tiles 0..127
  const int bl  = lane & 15;                       // local batch (tile 0); +16 tile 1
  const int bA  = B0 + bl;                         // global batch (tile 0)
  const int hi  = lane >> 4;                       // 0..3
  const int koff = hi * 8;
  const int ulA = 8 * wave + hi;                   // unit-local in WG's 32-slice
  const int ulB = ulA + 4;
  const int uA  = U0 + ulA;                        // global unit ids
  const int uB  = U0 + ulB;
  const float4 biasA = *reinterpret_cast<const float4*>(biasp + mtA * 16 + hi * 4);
  const float4 biasB = *reinterpret_cast<const float4*>(biasp + mtB * 16 + hi * 4);

  // preload both weight slices: 2 x 18 k-tiles x 8 bf16/lane = 144 VGPRs
  short8 wA[18], wB[18];
  {
    const u16* wa = wp + (size_t)mtA * (18 * 512) + lane * 8;
    const u16* wb = wp + (size_t)mtB * (18 * 512) + lane * 8;
    #pragma unroll
    for (int kt = 0; kt < 18; ++kt) {
      wA[kt] = *reinterpret_cast<const short8*>(wa + kt * 512);
      wB[kt] = *reinterpret_cast<const short8*>(wb + kt * 512);
    }
  }

  unsigned* cnt = bar;                             // single sync counter (round-12 wiring)
  float cA0 = 0.f, cA1 = 0.f, cB0 = 0.f, cB1 = 0.f;
  f32x4 accA0, accA1, accB0, accB1;

  // LDS fragment-read constants (local rows bl / bl+16; swizzle by row&7)
  const int r0base = bl * 1024;
  const int r1base = r0base + 16 * 1024;
  const int rmask  = (bl & 7) << 4;                // (bl+16)&7 == bl&7
  const int fr_hib = hi * 16;

#define XPART(T) do { \
    const u16* xt_ = seq + (size_t)(T) * 4096; \
    short8 x0a = *reinterpret_cast<const short8*>(xt_ + bA * 64 + koff); \
    short8 x1a = *reinterpret_cast<const short8*>(xt_ + (bA + 16) * 64 + koff); \
    short8 x0b = *reinterpret_cast<const short8*>(xt_ + bA * 64 + 32 + koff); \
    short8 x1b = *reinterpret_cast<const short8*>(xt_ + (bA + 16) * 64 + 32 + koff); \
    f32x4 z_ = {0.f, 0.f, 0.f, 0.f}; \
    accA0 = __builtin_amdgcn_mfma_f32_16x16x32_bf16(wA[0], x0a, z_, 0, 0, 0); \
    accA1 = __builtin_amdgcn_mfma_f32_16x16x32_bf16(wA[0], x1a, z_, 0, 0, 0); \
    accB0 = __builtin_amdgcn_mfma_f32_16x16x32_bf16(wB[0], x0a, z_, 0, 0, 0); \
    accB1 = __builtin_amdgcn_mfma_f32_16x16x32_bf16(wB[0], x1a, z_, 0, 0, 0); \
    accA0 = __builtin_amdgcn_mfma_f32_16x16x32_bf16(wA[1], x0b, accA0, 0, 0, 0); \
    accA1 = __builtin_amdgcn_mfma_f32_16x16x32_bf16(wA[1], x1b, accA1, 0, 0, 0); \
    accB0 = __builtin_amdgcn_mfma_f32_16x16x32_bf16(wB[1], x0b, accB0, 0, 0, 0); \
    accB1 = __builtin_amdgcn_mfma_f32_16x16x32_bf16(wB[1], x1b, accB1, 0, 0, 0); \
  } while (0)

  XPART(0);                                        // x-part for t=0 (h(-1)=0)

  for (int t = 0; t < TP; ++t) {
    // ---- wait for h(t-1): ONE RMW per WG per poll iteration at the XCD L2
    if (t > 0) {
      if (tid == 0) {
        const unsigned tgt = (unsigned)(NWRK * t);
        for (;;) {
          unsigned v = __hip_atomic_fetch_add(cnt, 0u, __ATOMIC_RELAXED,
                                              __HIP_MEMORY_SCOPE_WORKGROUP);
          if (v >= tgt) break;
          __builtin_amdgcn_s_sleep(1);
        }
      }
      __syncthreads();
    }

    const u16* hc = (t & 1) ? h1buf : h0buf;
    u16* hn = (t & 1) ? h0buf : h1buf;

    // ---- stage the GROUP's 32KB h-half into swizzled LDS: coalesced sc0 loads.
    // chunk = pass*256 + tid (16B each); a wave covers one 1KB row per pass.
    {
      const u16* hsrc = hc + (size_t)B0 * 512;
      f32x4 va[4], vb[4];
      #pragma unroll
      for (int p = 0; p < 4; ++p)
        va[p] = load16_sc0(hsrc + (size_t)(p * 256 + tid) * 8);
      #pragma unroll
      for (int p = 0; p < 4; ++p)
        vb[p] = load16_sc0(hsrc + (size_t)((p + 4) * 256 + tid) * 8);
      asm volatile("s_waitcnt vmcnt(4)" ::: "memory");
      __builtin_amdgcn_sched_barrier(0);
      #pragma unroll
      for (int p = 0; p < 4; ++p) {
        int chunk = p * 256 + tid;
        int row = chunk >> 6, off = (chunk & 63) * 16;
        *reinterpret_cast<f32x4*>(hl + row * 1024 + (off ^ ((row & 7) << 4))) = va[p];
      }
      asm volatile("s_waitcnt vmcnt(0)" ::: "memory");
      __builtin_amdgcn_sched_barrier(0);
      #pragma unroll
      for (int p = 0; p < 4; ++p) {
        int chunk = (p + 4) * 256 + tid;
        int row = chunk >> 6, off = (chunk & 63) * 16;
        *reinterpret_cast<f32x4*>(hl + row * 1024 + (off ^ ((row & 7) << 4))) = vb[p];
      }
    }
    __syncthreads();

    // ---- recurrent MFMAs: B-fragments from swizzled LDS (even bank spread)
    #pragma unroll
    for (int kt = 0; kt < 16; ++kt) {
      int off = (kt * 64 + fr_hib) ^ rmask;
      short8 b0 = *reinterpret_cast<const short8*>(hl + r0base + off);
      short8 b1 = *reinterpret_cast<const short8*>(hl + r1base + off);
      accA0 = __builtin_amdgcn_mfma_f32_16x16x32_bf16(wA[kt + 2], b0, accA0, 0, 0, 0);
      accA1 = __builtin_amdgcn_mfma_f32_16x16x32_bf16(wA[kt + 2], b1, accA1, 0, 0, 0);
      accB0 = __builtin_amdgcn_mfma_f32_16x16x32_bf16(wB[kt + 2], b0, accB0, 0, 0, 0);
      accB1 = __builtin_amdgcn_mfma_f32_16x16x32_bf16(wB[kt + 2], b1, accB1, 0, 0, 0);
    }

    // ---- gates (i,f,g,o in acc[0..3] of each lane, per mt x batch-tile)
    float iA0 = sigmoidf_(accA0[0] + biasA.x);
    float fA0 = sigmoidf_(accA0[1] + biasA.y);
    float gA0 = tanhf_(accA0[2] + biasA.z);
    float oA0 = sigmoidf_(accA0[3] + biasA.w);
    cA0 = fA0 * cA0 + iA0 * gA0;
    float hvA0 = oA0 * tanhf_(cA0);
    float iA1 = sigmoidf_(accA1[0] + biasA.x);
    float fA1 = sigmoidf_(accA1[1] + biasA.y);
    float gA1 = tanhf_(accA1[2] + biasA.z);
    float oA1 = sigmoidf_(accA1[3] + biasA.w);
    cA1 = fA1 * cA1 + iA1 * gA1;
    float hvA1 = oA1 * tanhf_(cA1);
    float iB0 = sigmoidf_(accB0[0] + biasB.x);
    float fB0 = sigmoidf_(accB0[1] + biasB.y);
    float gB0 = tanhf_(accB0[2] + biasB.z);
    float oB0 = sigmoidf_(accB0[3] + biasB.w);
    cB0 = fB0 * cB0 + iB0 * gB0;
    float hvB0 = oB0 * tanhf_(cB0);
    float iB1 = sigmoidf_(accB1[0] + biasB.x);
    float fB1 = sigmoidf_(accB1[1] + biasB.y);
    float gB1 = tanhf_(accB1[2] + biasB.z);
    float oB1 = sigmoidf_(accB1[3] + biasB.w);
    cB1 = fB1 * cB1 + iB1 * gB1;
    float hvB1 = oB1 * tanhf_(cB1);

    // ---- stage h slice (32 batches x 32 units) in padded LDS
    ostage[bl][ulA]      = f2bf(hvA0);
    ostage[bl + 16][ulA] = f2bf(hvA1);
    ostage[bl][ulB]      = f2bf(hvB0);
    ostage[bl + 16][ulB] = f2bf(hvB1);
    if (t == TP - 1) {
      hfin[bA * 512 + uA]        = hvA0;
      hfin[(bA + 16) * 512 + uA] = hvA1;
      hfin[bA * 512 + uB]        = hvB0;
      hfin[(bA + 16) * 512 + uB] = hvB1;
    }
    __syncthreads();

    // ---- coalesced sc0 h stores: 128 threads x 16B into XCD L2
    if (tid < 128) {
      int b_l = tid >> 2, q = tid & 3;
      f32x4 val = *reinterpret_cast<const f32x4*>(&ostage[b_l][q * 8]);
      store16_sc0(hn + (size_t)(B0 + b_l) * 512 + U0 + q * 8, val);
    }
    asm volatile("s_waitcnt vmcnt(0)" ::: "memory");
    __syncthreads();                               // all waves' stores drained

    // ---- signal: ONE atomic RMW per WG (L2 execution point = visibility)
    if (tid == 0)
      __hip_atomic_fetch_add(cnt, 1u, __ATOMIC_RELAXED, __HIP_MEMORY_SCOPE_WORKGROUP);

    // ---- x-part prefetch for t+1 (plain cached loads) overlaps others' polls
    if (t + 1 < TP) XPART(t + 1);
  }
#undef XPART

  // ---- tell the clock keepers we're done (MALL-scope RMW, cross-XCD visible)
  if (tid == 0)
    __hip_atomic_fetch_add(&bar[64], 1u, __ATOMIC_RELAXED, __HIP_MEMORY_SCOPE_AGENT);
}

// ---- final linear: out[b][o] = h . lin_w[o] + lin_b[o]  (fp32)
__global__ void k_fc(const float* __restrict__ hfin, const float* __restrict__ lin_w,
                     const float* __restrict__ lin_b, float* __restrict__ out) {
  int b = blockIdx.x, o = threadIdx.x;             // 128 threads
  const float* hp = hfin + b * 512;
  const float* wq = lin_w + o * 512;
  float s = lin_b[o];
  #pragma unroll 4
  for (int j = 0; j < 512; ++j) s += hp[j] * wq[j];
  out[b * 128 + o] = s;
}

extern "C" void kernel_launch(void* const* d_in, const int* in_sizes, int n_in,
                              void* d_out, int out_size, void* d_ws, size_t ws_size,
                              hipStream_t stream) {
  const float* inX    = (const float*)d_in[0];
  const float* conv_w = (const float*)d_in[2];
  const float* conv_b = (const float*)d_in[3];
  const float* w_ih   = (const float*)d_in[4];
  const float* w_hh   = (const float*)d_in[5];
  const float* b_ih   = (const float*)d_in[6];
  const float* b_hh   = (const float*)d_in[7];
  const float* lin_w  = (const float*)d_in[8];
  const float* lin_b  = (const float*)d_in[9];
  float* out = (float*)d_out;
  char* ws = (char*)d_ws;
  u16*      wpack = (u16*)(ws + OFF_WPACK);
  u16*      seq   = (u16*)(ws + OFF_SEQ);
  float*    biasp = (float*)(ws + OFF_BIAS);
  u16*      h0b   = (u16*)(ws + OFF_H0);
  u16*      h1b   = (u16*)(ws + OFF_H1);
  float*    hfin  = (float*)(ws + OFF_HFIN);
  unsigned* bar   = (unsigned*)(ws + OFF_BAR);

  k_init<<<dim3(128), dim3(256), 0, stream>>>(b_ih, b_hh, biasp, (unsigned*)(ws + OFF_H0), bar);
  k_pack<<<dim3(4608), dim3(256), 0, stream>>>(w_ih, w_hh, wpack);
  k_conv<<<dim3(256, 64), dim3(256), 0, stream>>>(inX, conv_w, conv_b, seq);
  k_lstm<<<dim3(256), dim3(256), 0, stream>>>(seq, wpack, biasp, h0b, h1b, hfin, bar);
  k_fc<<<dim3(64), dim3(128), 0, stream>>>(hfin, lin_w, lin_b, out);
}